// Round 1
// baseline (684.423 us; speedup 1.0000x reference)
//
#include <hip/hip_runtime.h>
#include <cstdint>

#define S_LEN 2048
#define D_DIM 4096
#define NH_ 32
#define NKV_ 8
#define HD_ 128
#define GK 4096

typedef unsigned short u16;
typedef __attribute__((ext_vector_type(4))) float f32x4;
typedef __attribute__((ext_vector_type(8))) short bf16x8;
typedef __attribute__((ext_vector_type(4))) short s16x4;

__device__ __forceinline__ short f2bf(float f) {
  union { float f; unsigned int u; } v; v.f = f;
  unsigned int r = v.u + 0x7fffu + ((v.u >> 16) & 1u);
  return (short)(r >> 16);
}

__device__ __forceinline__ void glds16(const void* g, void* l) {
  __builtin_amdgcn_global_load_lds(
      (const __attribute__((address_space(1))) void*)g,
      (__attribute__((address_space(3))) void*)l, 16, 0, 0);
}

// ---------------------------------------------------------------------------
// fp32 -> bf16 convert, 8 elems/thread
// ---------------------------------------------------------------------------
__global__ __launch_bounds__(256) void cvt_bf16(const float* __restrict__ src,
                                                u16* __restrict__ dst, int n8) {
  int i = blockIdx.x * 256 + threadIdx.x;
  if (i < n8) {
    float4 a = *(const float4*)&src[(size_t)i * 8];
    float4 b = *(const float4*)&src[(size_t)i * 8 + 4];
    bf16x8 o = { f2bf(a.x), f2bf(a.y), f2bf(a.z), f2bf(a.w),
                 f2bf(b.x), f2bf(b.y), f2bf(b.z), f2bf(b.w) };
    *(bf16x8*)&dst[(size_t)i * 8] = o;
  }
}

// ---------------------------------------------------------------------------
// 256x256 8-phase bf16 GEMM (T2+T3+T4+T5): C[M x N] = A[M x 4096]*W[N x 4096]^T
// 512 thr / 8 waves (2M x 4N), BK=64, 128 KiB double-buffered LDS, XOR block
// swizzle LDS[r][blk] = G[r][blk ^ (r&7)] (involution: pre-swizzled glds source,
// swizzled ds_read). Per K-tile: 4 phases = C-quadrants (m-half x n-half) x K=64,
// 16 MFMA each; 1 half-tile (2 glds/thr) staged per phase; counted
// s_waitcnt vmcnt(6) once per K-tile (3 half-tiles stay in flight).
// Half-tile stream order (B.h0,B.h1,A.h0,A.h1) vs front-loaded reads (all B +
// A.h0-reads in ph0, A.h1 reads in ph2) gives >=1-phase margin on every
// in-flight write into the currently-read buffer.
// MODE 0: plain fp32 C. MODE 1: fused QKV epilogue (N=6144) with RoPE.
// ---------------------------------------------------------------------------
template <int MODE>
__global__ __launch_bounds__(512, 1) void gemm8(const u16* __restrict__ Amat,
                                                const u16* __restrict__ W,
                                                float* __restrict__ C,
                                                u16* __restrict__ qbf,
                                                u16* __restrict__ kbf,
                                                u16* __restrict__ vbf,
                                                float* __restrict__ cko,
                                                float* __restrict__ cvo,
                                                const float* __restrict__ fc,
                                                const float* __restrict__ fs,
                                                int N) {
  __shared__ __align__(16) u16 As[2][16384];  // 2 x 32 KB
  __shared__ __align__(16) u16 Bs[2][16384];  // 2 x 32 KB
  const int t = threadIdx.x;
  const int lane = t & 63;
  const int wave = t >> 6;        // 0..7
  const int wr = wave >> 2;       // 0..1  M half
  const int wc = wave & 3;        // 0..3  N quarter
  const int quad = lane >> 4;
  const int L = lane & 15;
  const int bm = blockIdx.y * 256;
  const int bn = blockIdx.x * 256;
  const int dr = lane >> 3;       // row within 8-row chunk
  const int cb = lane & 7;        // 16B block within 128B row
  const int cbs = cb ^ dr;        // pre-swizzled source block
  const int NT = GK / 64;         // 64 K-tiles

  // half-tile stream: s -> tile = s>>2, part = s&3 (0:B.h0 1:B.h1 2:A.h0 3:A.h1)
  auto stage = [&](int s) {
    const int tile = s >> 2;
    const int p = s & 3;
    const int half = p & 1;
    const int buf = tile & 1;
    const int k0 = tile << 6;
    const bool isB = (p < 2);
    const u16* src = isB ? W : Amat;
    const int base = isB ? bn : bm;
    u16* dst = isB ? &Bs[buf][0] : &As[buf][0];
    const int chunk0 = half * 16 + wave * 2;
#pragma unroll
    for (int c = 0; c < 2; ++c) {
      const int chunk = chunk0 + c;
      const int row = chunk * 8 + dr;
      glds16(&src[(size_t)(base + row) * GK + k0 + cbs * 8], &dst[chunk * 512]);
    }
  };

  f32x4 acc[8][4];
#pragma unroll
  for (int i = 0; i < 8; ++i)
#pragma unroll
    for (int j = 0; j < 4; ++j) { f32x4 z = {0.f, 0.f, 0.f, 0.f}; acc[i][j] = z; }

  // prologue: tile0 complete + tile1 parts 0..2 in flight
  stage(0); stage(1); stage(2); stage(3);
  asm volatile("s_waitcnt vmcnt(4)" ::: "memory");
  stage(4); stage(5); stage(6);
  asm volatile("s_waitcnt vmcnt(6)" ::: "memory");
  __builtin_amdgcn_s_barrier();
  __builtin_amdgcn_sched_barrier(0);

  bf16x8 af[4][2], bw[4][2];
  const int arow = wr * 128;
  const int brow = wc * 64;

  for (int kt = 0; kt < NT; ++kt) {
    const u16* as = &As[kt & 1][0];
    const u16* bs = &Bs[kt & 1][0];
    // ---- phase 0: read af(m-half0) + ALL bw; stage tile+1 A.h1; MFMA (0,0)
#pragma unroll
    for (int i = 0; i < 4; ++i)
#pragma unroll
      for (int k = 0; k < 2; ++k)
        af[i][k] = *(const bf16x8*)&as[(arow + i * 16 + L) * 64 +
                                       (((k * 4 + quad) ^ (L & 7)) * 8)];
#pragma unroll
    for (int j = 0; j < 4; ++j)
#pragma unroll
      for (int k = 0; k < 2; ++k)
        bw[j][k] = *(const bf16x8*)&bs[(brow + j * 16 + L) * 64 +
                                       (((k * 4 + quad) ^ (L & 7)) * 8)];
    { int s = 4 * kt + 7; if (s < 4 * NT) stage(s); }
    __builtin_amdgcn_s_barrier();
    asm volatile("s_waitcnt lgkmcnt(0)" ::: "memory");
    __builtin_amdgcn_sched_barrier(0);
    __builtin_amdgcn_s_setprio(1);
#pragma unroll
    for (int i = 0; i < 4; ++i)
#pragma unroll
      for (int j = 0; j < 2; ++j)
#pragma unroll
        for (int k = 0; k < 2; ++k)
          acc[i][j] = __builtin_amdgcn_mfma_f32_16x16x32_bf16(af[i][k], bw[j][k],
                                                              acc[i][j], 0, 0, 0);
    __builtin_amdgcn_s_setprio(0);
    __builtin_amdgcn_s_barrier();
    // ---- phase 1: stage tile+2 B.h0; MFMA (0,1)
    { int s = 4 * kt + 8; if (s < 4 * NT) stage(s); }
    __builtin_amdgcn_s_barrier();
    __builtin_amdgcn_s_setprio(1);
#pragma unroll
    for (int i = 0; i < 4; ++i)
#pragma unroll
      for (int j = 0; j < 2; ++j)
#pragma unroll
        for (int k = 0; k < 2; ++k)
          acc[i][2 + j] = __builtin_amdgcn_mfma_f32_16x16x32_bf16(
              af[i][k], bw[2 + j][k], acc[i][2 + j], 0, 0, 0);
    __builtin_amdgcn_s_setprio(0);
    __builtin_amdgcn_s_barrier();
    // ---- phase 2: read af(m-half1); stage tile+2 B.h1; MFMA (1,0)
#pragma unroll
    for (int i = 0; i < 4; ++i)
#pragma unroll
      for (int k = 0; k < 2; ++k)
        af[i][k] = *(const bf16x8*)&as[(arow + 64 + i * 16 + L) * 64 +
                                       (((k * 4 + quad) ^ (L & 7)) * 8)];
    { int s = 4 * kt + 9; if (s < 4 * NT) stage(s); }
    __builtin_amdgcn_s_barrier();
    asm volatile("s_waitcnt lgkmcnt(0)" ::: "memory");
    __builtin_amdgcn_sched_barrier(0);
    __builtin_amdgcn_s_setprio(1);
#pragma unroll
    for (int i = 0; i < 4; ++i)
#pragma unroll
      for (int j = 0; j < 2; ++j)
#pragma unroll
        for (int k = 0; k < 2; ++k)
          acc[4 + i][j] = __builtin_amdgcn_mfma_f32_16x16x32_bf16(
              af[i][k], bw[j][k], acc[4 + i][j], 0, 0, 0);
    __builtin_amdgcn_s_setprio(0);
    __builtin_amdgcn_s_barrier();
    // ---- phase 3: stage tile+2 A.h0; MFMA (1,1); counted drain
    { int s = 4 * kt + 10; if (s < 4 * NT) stage(s); }
    __builtin_amdgcn_s_barrier();
    __builtin_amdgcn_s_setprio(1);
#pragma unroll
    for (int i = 0; i < 4; ++i)
#pragma unroll
      for (int j = 0; j < 2; ++j)
#pragma unroll
        for (int k = 0; k < 2; ++k)
          acc[4 + i][2 + j] = __builtin_amdgcn_mfma_f32_16x16x32_bf16(
              af[i][k], bw[2 + j][k], acc[4 + i][2 + j], 0, 0, 0);
    __builtin_amdgcn_s_setprio(0);
    if (kt + 2 < NT) asm volatile("s_waitcnt vmcnt(6)" ::: "memory");
    else             asm volatile("s_waitcnt vmcnt(0)" ::: "memory");
    __builtin_amdgcn_s_barrier();
    __builtin_amdgcn_sched_barrier(0);
  }

  if (MODE == 0) {
#pragma unroll
    for (int mi = 0; mi < 8; ++mi) {
      int r0 = bm + wr * 128 + mi * 16 + quad * 4;
#pragma unroll
      for (int ni = 0; ni < 4; ++ni) {
        int c = bn + wc * 64 + ni * 16 + L;
#pragma unroll
        for (int r = 0; r < 4; ++r) C[(size_t)(r0 + r) * N + c] = acc[mi][ni][r];
      }
    }
  } else {
    const float scale = 0.08838834764831845f;  // 1/sqrt(128)
#pragma unroll
    for (int mi = 0; mi < 8; ++mi) {
#pragma unroll
      for (int ni = 0; ni < 4; ++ni) {
        int c = bn + wc * 64 + ni * 16 + L;
#pragma unroll
        for (int r = 0; r < 4; ++r) {
          int srow = bm + wr * 128 + mi * 16 + 4 * quad + r;
          float v = acc[mi][ni][r];
          float partner = __shfl_xor(v, 1);  // all lanes, before branch
          if (c < 4096) {
            int p = (c >> 1) & 63;
            float co = fc[srow * 64 + p], si = fs[srow * 64 + p];
            float out = (c & 1) ? partner * si + v * co : v * co - partner * si;
            qbf[(size_t)srow * 4096 + c] = (u16)f2bf(out * scale);
          } else if (c < 5120) {
            int p = (c >> 1) & 63;
            float co = fc[srow * 64 + p], si = fs[srow * 64 + p];
            float out = (c & 1) ? partner * si + v * co : v * co - partner * si;
            int cc = c - 4096;
            cko[(size_t)srow * 1024 + cc] = out;
            kbf[(size_t)srow * 1024 + cc] = (u16)f2bf(out);
          } else {
            int cc = c - 5120;
            cvo[(size_t)srow * 1024 + cc] = v;
            vbf[(size_t)srow * 1024 + cc] = (u16)f2bf(v);
          }
        }
      }
    }
  }
}

// ---------------------------------------------------------------------------
// MFMA flash attention, bf16 inputs (q_bf pre-scaled, k_bf, v_bf), bf16 out.
// Unchanged from verified round (4 waves x 16 q-rows, 64-k tiles).
// ---------------------------------------------------------------------------
__global__ __launch_bounds__(256, 3) void attn_bf(const u16* __restrict__ qbf,
                                                  const u16* __restrict__ kbf,
                                                  const u16* __restrict__ vbf,
                                                  u16* __restrict__ ao) {
  __shared__ __align__(16) u16 Ks[64 * 136];
  __shared__ __align__(16) u16 Vt[128 * 64];
  __shared__ __align__(16) u16 Ps[4 * 16 * 72];
  const int t = threadIdx.x;
  const int wave = t >> 6;
  const int lane = t & 63;
  const int Q4 = lane >> 4;
  const int L = lane & 15;
  const int h = blockIdx.y;
  const int qb = 31 - (int)blockIdx.x;
  const int kvh = h >> 2;
  const int qs0 = qb * 64;
  u16* Psw = &Ps[wave * 16 * 72];

  bf16x8 qf[4];
  {
    const u16* qbase = &qbf[(size_t)(qs0 + 16 * wave + L) * D_DIM + h * HD_ + 8 * Q4];
#pragma unroll
    for (int s = 0; s < 4; ++s) qf[s] = *(const bf16x8*)&qbase[32 * s];
  }

  f32x4 o[8];
#pragma unroll
  for (int jd = 0; jd < 8; ++jd) { f32x4 z = {0.f, 0.f, 0.f, 0.f}; o[jd] = z; }
  float mold[4] = {-1e30f, -1e30f, -1e30f, -1e30f};
  float lst[4] = {0.f, 0.f, 0.f, 0.f};

  for (int kt = 0; kt <= qb; ++kt) {
    __syncthreads();
    const u16* kb = &kbf[(size_t)(kt * 64) * (NKV_ * HD_) + kvh * HD_];
    const u16* vb = &vbf[(size_t)(kt * 64) * (NKV_ * HD_) + kvh * HD_];
#pragma unroll
    for (int p = 0; p < 4; ++p) {           // K: 64 rows x 256B
      int u = t + 256 * p;
      int r = u >> 4, c8 = u & 15;
      *(bf16x8*)&Ks[r * 136 + c8 * 8] =
          *(const bf16x8*)&kb[(size_t)r * (NKV_ * HD_) + c8 * 8];
    }
#pragma unroll
    for (int p = 0; p < 4; ++p) {           // V: transpose + block rotation
      int u = t + 256 * p;
      int d = u & 127, bb = u >> 7;
      const u16* vsrc = &vb[(size_t)(bb * 8) * (NKV_ * HD_) + d];
      short vv[8];
#pragma unroll
      for (int j = 0; j < 8; ++j) vv[j] = (short)vsrc[(size_t)j * (NKV_ * HD_)];
      bf16x8 pk = { vv[0], vv[1], vv[2], vv[3], vv[4], vv[5], vv[6], vv[7] };
      *(bf16x8*)&Vt[d * 64 + ((bb + d) & 7) * 8] = pk;
    }
    __syncthreads();

    f32x4 sa[4];
#pragma unroll
    for (int jn = 0; jn < 4; ++jn) { f32x4 z = {0.f, 0.f, 0.f, 0.f}; sa[jn] = z; }
#pragma unroll
    for (int s = 0; s < 4; ++s) {
#pragma unroll
      for (int jn = 0; jn < 4; ++jn) {
        bf16x8 kf = *(const bf16x8*)&Ks[(16 * jn + L) * 136 + 32 * s + 8 * Q4];
        sa[jn] = __builtin_amdgcn_mfma_f32_16x16x32_bf16(qf[s], kf, sa[jn], 0, 0, 0);
      }
    }

    const int gq0 = qs0 + 16 * wave + 4 * Q4;
    const int gk0 = kt * 64 + L;
    float rmax[4];
#pragma unroll
    for (int r = 0; r < 4; ++r) {
#pragma unroll
      for (int jn = 0; jn < 4; ++jn)
        if (gk0 + 16 * jn > gq0 + r) sa[jn][r] = -1e30f;
      rmax[r] = fmaxf(fmaxf(sa[0][r], sa[1][r]), fmaxf(sa[2][r], sa[3][r]));
    }
#pragma unroll
    for (int m = 1; m < 16; m <<= 1) {
#pragma unroll
      for (int r = 0; r < 4; ++r) rmax[r] = fmaxf(rmax[r], __shfl_xor(rmax[r], m));
    }
    float p_[4][4], rsum[4], alpha[4];
#pragma unroll
    for (int r = 0; r < 4; ++r) {
      float mnew = fmaxf(mold[r], rmax[r]);
      alpha[r] = __expf(mold[r] - mnew);
#pragma unroll
      for (int jn = 0; jn < 4; ++jn) p_[jn][r] = __expf(sa[jn][r] - mnew);
      rsum[r] = (p_[0][r] + p_[1][r]) + (p_[2][r] + p_[3][r]);
      mold[r] = mnew;
    }
#pragma unroll
    for (int m = 1; m < 16; m <<= 1) {
#pragma unroll
      for (int r = 0; r < 4; ++r) rsum[r] += __shfl_xor(rsum[r], m);
    }
#pragma unroll
    for (int r = 0; r < 4; ++r) lst[r] = lst[r] * alpha[r] + rsum[r];
#pragma unroll
    for (int jd = 0; jd < 8; ++jd)
#pragma unroll
      for (int r = 0; r < 4; ++r) o[jd][r] *= alpha[r];

#pragma unroll
    for (int r = 0; r < 4; ++r)
#pragma unroll
      for (int jn = 0; jn < 4; ++jn)
        Psw[(4 * Q4 + r) * 72 + 16 * jn + L] = (u16)f2bf(p_[jn][r]);
    asm volatile("s_waitcnt lgkmcnt(0)" ::: "memory");

#pragma unroll
    for (int s2 = 0; s2 < 2; ++s2) {
      bf16x8 pa = *(const bf16x8*)&Psw[L * 72 + 32 * s2 + 8 * Q4];
#pragma unroll
      for (int jd = 0; jd < 8; ++jd) {
        bf16x8 vf = *(const bf16x8*)&Vt[(16 * jd + L) * 64 + ((4 * s2 + Q4 + L) & 7) * 8];
        o[jd] = __builtin_amdgcn_mfma_f32_16x16x32_bf16(pa, vf, o[jd], 0, 0, 0);
      }
    }
  }

  float inv[4];
#pragma unroll
  for (int r = 0; r < 4; ++r) inv[r] = 1.0f / lst[r];
#pragma unroll
  for (int r = 0; r < 4; ++r) {
    u16* dst = &ao[(size_t)(qs0 + 16 * wave + 4 * Q4 + r) * D_DIM + h * HD_ + L];
#pragma unroll
    for (int jd = 0; jd < 8; ++jd) dst[16 * jd] = (u16)f2bf(o[jd][r] * inv[r]);
  }
}

// ===========================================================================
// Fallback path (round-2 kernels, verified) for small ws_size
// ===========================================================================
#define LDA 40
__global__ __launch_bounds__(256) void gemm_bt(const float* __restrict__ A,
                                               const float* __restrict__ W,
                                               float* __restrict__ C, int N) {
  __shared__ short As[128 * LDA];
  __shared__ short Bs[128 * LDA];
  const int t = threadIdx.x;
  const int lane = t & 63;
  const int wave = t >> 6;
  const int wm = (wave >> 1) * 64;
  const int wn = (wave & 1) * 64;
  const int quad = lane >> 4;
  const int l15 = lane & 15;
  const int bm = blockIdx.y * 128;
  const int bn = blockIdx.x * 128;
  f32x4 acc[4][4];
#pragma unroll
  for (int i = 0; i < 4; ++i)
#pragma unroll
    for (int j = 0; j < 4; ++j) { f32x4 z = {0.f, 0.f, 0.f, 0.f}; acc[i][j] = z; }
  for (int k0 = 0; k0 < GK; k0 += 32) {
    __syncthreads();
#pragma unroll
    for (int p = 0; p < 4; ++p) {
      int idx = p * 256 + t;
      int row = idx >> 3;
      int c4 = (idx & 7) * 4;
      const float4 av = *(const float4*)&A[(size_t)(bm + row) * GK + k0 + c4];
      const float4 wv = *(const float4*)&W[(size_t)(bn + row) * GK + k0 + c4];
      s16x4 a4 = { f2bf(av.x), f2bf(av.y), f2bf(av.z), f2bf(av.w) };
      s16x4 w4 = { f2bf(wv.x), f2bf(wv.y), f2bf(wv.z), f2bf(wv.w) };
      *(s16x4*)&As[row * LDA + c4] = a4;
      *(s16x4*)&Bs[row * LDA + c4] = w4;
    }
    __syncthreads();
    bf16x8 af[4], bfr[4];
#pragma unroll
    for (int i = 0; i < 4; ++i) {
      af[i]  = *(const bf16x8*)&As[(wm + i * 16 + l15) * LDA + quad * 8];
      bfr[i] = *(const bf16x8*)&Bs[(wn + i * 16 + l15) * LDA + quad * 8];
    }
#pragma unroll
    for (int i = 0; i < 4; ++i)
#pragma unroll
      for (int j = 0; j < 4; ++j)
        acc[i][j] = __builtin_amdgcn_mfma_f32_16x16x32_bf16(af[i], bfr[j], acc[i][j], 0, 0, 0);
  }
#pragma unroll
  for (int i = 0; i < 4; ++i) {
    int r0 = bm + wm + i * 16 + quad * 4;
#pragma unroll
    for (int j = 0; j < 4; ++j) {
      int c = bn + wn + j * 16 + l15;
#pragma unroll
      for (int r = 0; r < 4; ++r) C[(size_t)(r0 + r) * N + c] = acc[i][j][r];
    }
  }
}

__global__ __launch_bounds__(256) void rope_kernel(float* __restrict__ xq,
                                                   const float* __restrict__ xk,
                                                   float* __restrict__ cko,
                                                   const float* __restrict__ fc,
                                                   const float* __restrict__ fs) {
  int i = blockIdx.x * 256 + threadIdx.x;
  const int NQP = S_LEN * NH_ * (HD_ / 2);
  if (i < NQP) {
    int s = i >> 11; int rem = i & 2047; int p = rem & 63;
    float c = fc[s * 64 + p], sn = fs[s * 64 + p];
    float2 v = *(const float2*)&xq[(size_t)s * D_DIM + 2 * rem];
    *(float2*)&xq[(size_t)s * D_DIM + 2 * rem] =
        make_float2(v.x * c - v.y * sn, v.x * sn + v.y * c);
  } else {
    int j = i - NQP; int s = j >> 9; int rem = j & 511; int p = rem & 63;
    float c = fc[s * 64 + p], sn = fs[s * 64 + p];
    float2 v = *(const float2*)&xk[(size_t)s * (NKV_ * HD_) + 2 * rem];
    *(float2*)&cko[(size_t)s * (NKV_ * HD_) + 2 * rem] =
        make_float2(v.x * c - v.y * sn, v.x * sn + v.y * c);
  }
}

__global__ __launch_bounds__(256, 3) void attn_mfma(const float* __restrict__ xq,
                                                    const float* __restrict__ ck,
                                                    const float* __restrict__ cv,
                                                    float* __restrict__ outp) {
  __shared__ __align__(16) short Ks[64 * 136];
  __shared__ __align__(16) short Vt[128 * 64];
  __shared__ __align__(16) short Ps[4 * 16 * 72];
  const int t = threadIdx.x;
  const int wave = t >> 6;
  const int lane = t & 63;
  const int Q4 = lane >> 4;
  const int L = lane & 15;
  const int h = blockIdx.y;
  const int qb = 31 - (int)blockIdx.x;
  const int kvh = h >> 2;
  const int qs0 = qb * 64;
  const float scale = 0.08838834764831845f;
  short* Psw = &Ps[wave * 16 * 72];
  bf16x8 qf[4];
  {
    const float* qbase = &xq[(size_t)(qs0 + 16 * wave + L) * D_DIM + h * HD_ + 8 * Q4];
#pragma unroll
    for (int s = 0; s < 4; ++s) {
      float4 a = *(const float4*)&qbase[32 * s];
      float4 b = *(const float4*)&qbase[32 * s + 4];
      bf16x8 q8 = { f2bf(a.x * scale), f2bf(a.y * scale), f2bf(a.z * scale), f2bf(a.w * scale),
                    f2bf(b.x * scale), f2bf(b.y * scale), f2bf(b.z * scale), f2bf(b.w * scale) };
      qf[s] = q8;
    }
  }
  f32x4 o[8];
#pragma unroll
  for (int jd = 0; jd < 8; ++jd) { f32x4 z = {0.f, 0.f, 0.f, 0.f}; o[jd] = z; }
  float mold[4] = {-1e30f, -1e30f, -1e30f, -1e30f};
  float lst[4] = {0.f, 0.f, 0.f, 0.f};
  for (int kt = 0; kt <= qb; ++kt) {
    __syncthreads();
    const float* ckb = &ck[(size_t)(kt * 64) * (NKV_ * HD_) + kvh * HD_];
    const float* cvb = &cv[(size_t)(kt * 64) * (NKV_ * HD_) + kvh * HD_];
#pragma unroll
    for (int p = 0; p < 8; ++p) {
      int i = t + 256 * p;
      int r = i >> 5, c4 = (i & 31) * 4;
      float4 v = *(const float4*)&ckb[(size_t)r * (NKV_ * HD_) + c4];
      s16x4 k4 = { f2bf(v.x), f2bf(v.y), f2bf(v.z), f2bf(v.w) };
      *(s16x4*)&Ks[r * 136 + c4] = k4;
    }
#pragma unroll
    for (int p = 0; p < 4; ++p) {
      int u = t + 256 * p;
      int d = u & 127, bb = u >> 7;
      float vv[8];
#pragma unroll
      for (int j = 0; j < 8; ++j) vv[j] = cvb[(size_t)(bb * 8 + j) * (NKV_ * HD_) + d];
      bf16x8 pk = { f2bf(vv[0]), f2bf(vv[1]), f2bf(vv[2]), f2bf(vv[3]),
                    f2bf(vv[4]), f2bf(vv[5]), f2bf(vv[6]), f2bf(vv[7]) };
      *(bf16x8*)&Vt[d * 64 + ((bb + d) & 7) * 8] = pk;
    }
    __syncthreads();
    f32x4 sa[4];
#pragma unroll
    for (int jn = 0; jn < 4; ++jn) { f32x4 z = {0.f, 0.f, 0.f, 0.f}; sa[jn] = z; }
#pragma unroll
    for (int s = 0; s < 4; ++s) {
#pragma unroll
      for (int jn = 0; jn < 4; ++jn) {
        bf16x8 kf = *(const bf16x8*)&Ks[(16 * jn + L) * 136 + 32 * s + 8 * Q4];
        sa[jn] = __builtin_amdgcn_mfma_f32_16x16x32_bf16(qf[s], kf, sa[jn], 0, 0, 0);
      }
    }
    const int gq0 = qs0 + 16 * wave + 4 * Q4;
    const int gk0 = kt * 64 + L;
    float rmax[4];
#pragma unroll
    for (int r = 0; r < 4; ++r) {
#pragma unroll
      for (int jn = 0; jn < 4; ++jn)
        if (gk0 + 16 * jn > gq0 + r) sa[jn][r] = -1e30f;
      rmax[r] = fmaxf(fmaxf(sa[0][r], sa[1][r]), fmaxf(sa[2][r], sa[3][r]));
    }
#pragma unroll
    for (int m = 1; m < 16; m <<= 1) {
#pragma unroll
      for (int r = 0; r < 4; ++r) rmax[r] = fmaxf(rmax[r], __shfl_xor(rmax[r], m));
    }
    float p_[4][4], rsum[4], alpha[4];
#pragma unroll
    for (int r = 0; r < 4; ++r) {
      float mnew = fmaxf(mold[r], rmax[r]);
      alpha[r] = __expf(mold[r] - mnew);
#pragma unroll
      for (int jn = 0; jn < 4; ++jn) p_[jn][r] = __expf(sa[jn][r] - mnew);
      rsum[r] = (p_[0][r] + p_[1][r]) + (p_[2][r] + p_[3][r]);
      mold[r] = mnew;
    }
#pragma unroll
    for (int m = 1; m < 16; m <<= 1) {
#pragma unroll
      for (int r = 0; r < 4; ++r) rsum[r] += __shfl_xor(rsum[r], m);
    }
#pragma unroll
    for (int r = 0; r < 4; ++r) lst[r] = lst[r] * alpha[r] + rsum[r];
#pragma unroll
    for (int jd = 0; jd < 8; ++jd)
#pragma unroll
      for (int r = 0; r < 4; ++r) o[jd][r] *= alpha[r];
#pragma unroll
    for (int r = 0; r < 4; ++r)
#pragma unroll
      for (int jn = 0; jn < 4; ++jn)
        Psw[(4 * Q4 + r) * 72 + 16 * jn + L] = f2bf(p_[jn][r]);
    asm volatile("s_waitcnt lgkmcnt(0)" ::: "memory");
#pragma unroll
    for (int s2 = 0; s2 < 2; ++s2) {
      bf16x8 pa = *(const bf16x8*)&Psw[L * 72 + 32 * s2 + 8 * Q4];
#pragma unroll
      for (int jd = 0; jd < 8; ++jd) {
        bf16x8 vf = *(const bf16x8*)&Vt[(16 * jd + L) * 64 + ((4 * s2 + Q4 + L) & 7) * 8];
        o[jd] = __builtin_amdgcn_mfma_f32_16x16x32_bf16(pa, vf, o[jd], 0, 0, 0);
      }
    }
  }
  float inv[4];
#pragma unroll
  for (int r = 0; r < 4; ++r) inv[r] = 1.0f / lst[r];
#pragma unroll
  for (int r = 0; r < 4; ++r) {
    float* dst = &outp[(size_t)(qs0 + 16 * wave + 4 * Q4 + r) * D_DIM + h * HD_ + L];
#pragma unroll
    for (int jd = 0; jd < 8; ++jd) dst[16 * jd] = o[jd][r] * inv[r];
  }
}

// ---------------------------------------------------------------------------
// Inputs: 0:x 1:fc 2:fs 3:mask(unused) 4:idx(unused) 5:ck0 6:cv0 7:wq 8:wk
// 9:wv 10:wo. d_out = [out | cache_k | cache_v].
// Fast path ws (bytes): x_bf 16.8M | wqkv 50.3M (wo reuses) | q_bf 16.8M |
// k_bf 4.2M | v_bf 4.2M | ao_bf 16.8M = 109,051,904 B. Else round-2 path.
// ---------------------------------------------------------------------------
extern "C" void kernel_launch(void* const* d_in, const int* in_sizes, int n_in,
                              void* d_out, int out_size, void* d_ws, size_t ws_size,
                              hipStream_t stream) {
  (void)in_sizes; (void)n_in; (void)out_size;
  const float* x  = (const float*)d_in[0];
  const float* fc = (const float*)d_in[1];
  const float* fs = (const float*)d_in[2];
  const float* wq = (const float*)d_in[7];
  const float* wk = (const float*)d_in[8];
  const float* wv = (const float*)d_in[9];
  const float* wo = (const float*)d_in[10];
  float* outp = (float*)d_out;
  float* ck = outp + (size_t)S_LEN * D_DIM;
  float* cv = ck + (size_t)S_LEN * NKV_ * HD_;

  if (ws_size >= 109051904ull) {
    u16* x_bf = (u16*)d_ws;                       //  8,388,608 elems
    u16* wqkv = x_bf + 8388608;                   // 25,165,824 elems
    u16* q_bf = wqkv + 25165824;                  //  8,388,608
    u16* k_bf = q_bf + 8388608;                   //  2,097,152
    u16* v_bf = k_bf + 2097152;                   //  2,097,152
    u16* ao_bf = v_bf + 2097152;                  //  8,388,608
    u16* wo_bf = wqkv;                            // reuse after qkv gemm

    cvt_bf16<<<4096, 256, 0, stream>>>(x, x_bf, 1048576);
    cvt_bf16<<<8192, 256, 0, stream>>>(wq, wqkv, 2097152);
    cvt_bf16<<<2048, 256, 0, stream>>>(wk, wqkv + 16777216, 524288);
    cvt_bf16<<<2048, 256, 0, stream>>>(wv, wqkv + 20971520, 524288);
    gemm8<1><<<dim3(24, 8), 512, 0, stream>>>(x_bf, wqkv, nullptr, q_bf,
                                              k_bf, v_bf, ck, cv, fc, fs, 6144);
    cvt_bf16<<<8192, 256, 0, stream>>>(wo, wo_bf, 2097152);
    attn_bf<<<dim3(32, 32), 256, 0, stream>>>(q_bf, k_bf, v_bf, ao_bf);
    gemm8<0><<<dim3(16, 8), 512, 0, stream>>>(ao_bf, wo_bf, outp, nullptr,
                                              nullptr, nullptr, nullptr,
                                              nullptr, fc, fs, 4096);
  } else {
    float* xq = (float*)d_ws;
    float* xk = xq + (size_t)S_LEN * D_DIM;
    dim3 blk(256);
    gemm_bt<<<dim3(32, 16), blk, 0, stream>>>(x, wq, xq, 4096);
    gemm_bt<<<dim3(8, 16),  blk, 0, stream>>>(x, wk, xk, 1024);
    gemm_bt<<<dim3(8, 16),  blk, 0, stream>>>(x, wv, cv, 1024);
    rope_kernel<<<20480, 256, 0, stream>>>(xq, xk, ck, fc, fs);
    attn_mfma<<<dim3(32, 32), 512 / 2, 0, stream>>>(xq, ck, cv, xq);
    gemm_bt<<<dim3(32, 16), blk, 0, stream>>>(xq, wo, outp, 4096);
  }
}

// Round 2
// 646.093 us; speedup vs baseline: 1.0593x; 1.0593x over previous
//
#include <hip/hip_runtime.h>
#include <cstdint>

#define S_LEN 2048
#define D_DIM 4096
#define NH_ 32
#define NKV_ 8
#define HD_ 128
#define GK 4096

typedef unsigned short u16;
typedef __attribute__((ext_vector_type(4))) float f32x4;
typedef __attribute__((ext_vector_type(8))) short bf16x8;
typedef __attribute__((ext_vector_type(4))) short s16x4;

__device__ __forceinline__ short f2bf(float f) {
  union { float f; unsigned int u; } v; v.f = f;
  unsigned int r = v.u + 0x7fffu + ((v.u >> 16) & 1u);
  return (short)(r >> 16);
}

__device__ __forceinline__ void glds16(const void* g, void* l) {
  __builtin_amdgcn_global_load_lds(
      (const __attribute__((address_space(1))) void*)g,
      (__attribute__((address_space(3))) void*)l, 16, 0, 0);
}

// ---------------------------------------------------------------------------
// fp32 -> bf16 convert, 8 elems/thread
// ---------------------------------------------------------------------------
__global__ __launch_bounds__(256) void cvt_bf16(const float* __restrict__ src,
                                                u16* __restrict__ dst, int n8) {
  int i = blockIdx.x * 256 + threadIdx.x;
  if (i < n8) {
    float4 a = *(const float4*)&src[(size_t)i * 8];
    float4 b = *(const float4*)&src[(size_t)i * 8 + 4];
    bf16x8 o = { f2bf(a.x), f2bf(a.y), f2bf(a.z), f2bf(a.w),
                 f2bf(b.x), f2bf(b.y), f2bf(b.z), f2bf(b.w) };
    *(bf16x8*)&dst[(size_t)i * 8] = o;
  }
}

// ---------------------------------------------------------------------------
// 256x256 8-phase bf16 GEMM, phase = (m-half x K-sub) for EVEN ds_read
// distribution (8,4,8,4 per phase vs old 16,0,8,0 which LDS-serialized ph0).
// 512 thr / 8 waves (2M x 4N), BK=64, 128 KiB double-buffered LDS, XOR block
// swizzle LDS[r][blk] = G[r][blk ^ (r&7)].
// Staging: ph0 stages A(kt+1) [other buf; A of cur buf last read ph3 of prev kt],
// ph3 stages B(kt+2) [cur buf; B last read ph2]. vmcnt(4) once per K-tile
// keeps B(kt+2)'s 4 loads in flight; drains A(kt+1)+B(kt+1) before next kt.
// MODE 0: plain fp32 C. MODE 1: fused QKV epilogue (N=6144) with RoPE.
// ---------------------------------------------------------------------------
template <int MODE>
__global__ __launch_bounds__(512, 2) void gemm8(const u16* __restrict__ Amat,
                                                const u16* __restrict__ W,
                                                float* __restrict__ C,
                                                u16* __restrict__ qbf,
                                                u16* __restrict__ kbf,
                                                u16* __restrict__ vbf,
                                                float* __restrict__ cko,
                                                float* __restrict__ cvo,
                                                const float* __restrict__ fc,
                                                const float* __restrict__ fs,
                                                int N) {
  __shared__ __align__(16) u16 As[2][16384];  // 2 x 32 KB
  __shared__ __align__(16) u16 Bs[2][16384];  // 2 x 32 KB
  const int t = threadIdx.x;
  const int lane = t & 63;
  const int wave = t >> 6;        // 0..7
  const int wr = wave >> 2;       // 0..1  M half
  const int wc = wave & 3;        // 0..3  N quarter
  const int quad = lane >> 4;
  const int L = lane & 15;
  const int bm = blockIdx.y * 256;
  const int bn = blockIdx.x * 256;
  const int dr = lane >> 3;       // row within 8-row chunk
  const int cb = lane & 7;        // 16B block within 128B row
  const int cbs = cb ^ dr;        // pre-swizzled source block
  const int NT = GK / 64;         // 64 K-tiles

  // full-tile stagers: 4 glds/thread each (256 rows x 64 k = 32 KB)
  auto stageA = [&](int tile) {
    u16* dst = &As[tile & 1][0];
    const int k0 = tile << 6;
#pragma unroll
    for (int c = 0; c < 4; ++c) {
      const int chunk = wave * 4 + c;        // 0..31, 8 rows each
      const int row = chunk * 8 + dr;
      glds16(&Amat[(size_t)(bm + row) * GK + k0 + cbs * 8], &dst[chunk * 512]);
    }
  };
  auto stageB = [&](int tile) {
    u16* dst = &Bs[tile & 1][0];
    const int k0 = tile << 6;
#pragma unroll
    for (int c = 0; c < 4; ++c) {
      const int chunk = wave * 4 + c;
      const int row = chunk * 8 + dr;
      glds16(&W[(size_t)(bn + row) * GK + k0 + cbs * 8], &dst[chunk * 512]);
    }
  };

  f32x4 acc[8][4];
#pragma unroll
  for (int i = 0; i < 8; ++i)
#pragma unroll
    for (int j = 0; j < 4; ++j) { f32x4 z = {0.f, 0.f, 0.f, 0.f}; acc[i][j] = z; }

  // prologue: tile0 complete, B(1) in flight (A(1) staged in kt0.ph0)
  stageB(0); stageA(0); stageB(1);
  asm volatile("s_waitcnt vmcnt(4)" ::: "memory");
  __builtin_amdgcn_s_barrier();
  __builtin_amdgcn_sched_barrier(0);

  bf16x8 af[4], bw[4];
  const int arow = wr * 128;
  const int brow = wc * 64;

  for (int kt = 0; kt < NT; ++kt) {
    const u16* as = &As[kt & 1][0];
    const u16* bs = &Bs[kt & 1][0];
#pragma unroll
    for (int ph = 0; ph < 4; ++ph) {
      const int mh = ph & 1;      // ph0:(m0,s0) ph1:(m1,s0) ph2:(m0,s1) ph3:(m1,s1)
      const int s = ph >> 1;
      // ---- ds reads: 4 af always; 4 bw on ph0/ph2 (bw reused by next phase)
#pragma unroll
      for (int i = 0; i < 4; ++i)
        af[i] = *(const bf16x8*)&as[(arow + mh * 64 + i * 16 + L) * 64 +
                                     (((s * 4 + quad) ^ (L & 7)) * 8)];
      if (ph == 0 || ph == 2) {
#pragma unroll
        for (int j = 0; j < 4; ++j)
          bw[j] = *(const bf16x8*)&bs[(brow + j * 16 + L) * 64 +
                                       (((s * 4 + quad) ^ (L & 7)) * 8)];
      }
      // ---- stage issue
      if (ph == 0 && kt + 1 < NT) stageA(kt + 1);
      if (ph == 3 && kt + 2 < NT) stageB(kt + 2);
      __builtin_amdgcn_s_barrier();
      asm volatile("s_waitcnt lgkmcnt(0)" ::: "memory");
      __builtin_amdgcn_sched_barrier(0);
      __builtin_amdgcn_s_setprio(1);
#pragma unroll
      for (int i = 0; i < 4; ++i)
#pragma unroll
        for (int j = 0; j < 4; ++j)
          acc[mh * 4 + i][j] = __builtin_amdgcn_mfma_f32_16x16x32_bf16(
              af[i], bw[j], acc[mh * 4 + i][j], 0, 0, 0);
      __builtin_amdgcn_s_setprio(0);
      if (ph == 3) {
        if (kt + 2 < NT) asm volatile("s_waitcnt vmcnt(4)" ::: "memory");
        else             asm volatile("s_waitcnt vmcnt(0)" ::: "memory");
      }
      __builtin_amdgcn_s_barrier();
      __builtin_amdgcn_sched_barrier(0);
    }
  }

  if (MODE == 0) {
#pragma unroll
    for (int mi = 0; mi < 8; ++mi) {
      int r0 = bm + wr * 128 + mi * 16 + quad * 4;
#pragma unroll
      for (int ni = 0; ni < 4; ++ni) {
        int c = bn + wc * 64 + ni * 16 + L;
#pragma unroll
        for (int r = 0; r < 4; ++r) C[(size_t)(r0 + r) * N + c] = acc[mi][ni][r];
      }
    }
  } else {
    const float scale = 0.08838834764831845f;  // 1/sqrt(128)
#pragma unroll
    for (int mi = 0; mi < 8; ++mi) {
#pragma unroll
      for (int ni = 0; ni < 4; ++ni) {
        int c = bn + wc * 64 + ni * 16 + L;
#pragma unroll
        for (int r = 0; r < 4; ++r) {
          int srow = bm + wr * 128 + mi * 16 + 4 * quad + r;
          float v = acc[mi][ni][r];
          float partner = __shfl_xor(v, 1);  // all lanes, before branch
          if (c < 4096) {
            int p = (c >> 1) & 63;
            float co = fc[srow * 64 + p], si = fs[srow * 64 + p];
            float out = (c & 1) ? partner * si + v * co : v * co - partner * si;
            qbf[(size_t)srow * 4096 + c] = (u16)f2bf(out * scale);
          } else if (c < 5120) {
            int p = (c >> 1) & 63;
            float co = fc[srow * 64 + p], si = fs[srow * 64 + p];
            float out = (c & 1) ? partner * si + v * co : v * co - partner * si;
            int cc = c - 4096;
            cko[(size_t)srow * 1024 + cc] = out;
            kbf[(size_t)srow * 1024 + cc] = (u16)f2bf(out);
          } else {
            int cc = c - 5120;
            cvo[(size_t)srow * 1024 + cc] = v;
            vbf[(size_t)srow * 1024 + cc] = (u16)f2bf(v);
          }
        }
      }
    }
  }
}

// ---------------------------------------------------------------------------
// MFMA flash attention, bf16 in/out. NOW 8 waves / 512 thr, QBLK=128/block:
// K/V staging amortized over 2x waves, 16 waves/CU (VGPR-capped).
// Per wave unchanged: 16 q-rows, 64-k tiles, C-layout softmax, P->LDS,
// Vt rotated-block transpose. Waves 0-3 see one fully-masked diagonal tile:
// safe (mold finite after kt=0 since col 0 is unmasked for every row).
// ---------------------------------------------------------------------------
__global__ __launch_bounds__(512, 2) void attn_bf(const u16* __restrict__ qbf,
                                                  const u16* __restrict__ kbf,
                                                  const u16* __restrict__ vbf,
                                                  u16* __restrict__ ao) {
  __shared__ __align__(16) u16 Ks[64 * 136];
  __shared__ __align__(16) u16 Vt[128 * 64];
  __shared__ __align__(16) u16 Ps[8 * 16 * 72];
  const int t = threadIdx.x;
  const int wave = t >> 6;          // 0..7
  const int lane = t & 63;
  const int Q4 = lane >> 4;
  const int L = lane & 15;
  const int h = blockIdx.y;
  const int qb = 15 - (int)blockIdx.x;
  const int kvh = h >> 2;
  const int qs0 = qb * 128;
  u16* Psw = &Ps[wave * 16 * 72];

  bf16x8 qf[4];
  {
    const u16* qbase = &qbf[(size_t)(qs0 + 16 * wave + L) * D_DIM + h * HD_ + 8 * Q4];
#pragma unroll
    for (int s = 0; s < 4; ++s) qf[s] = *(const bf16x8*)&qbase[32 * s];
  }

  f32x4 o[8];
#pragma unroll
  for (int jd = 0; jd < 8; ++jd) { f32x4 z = {0.f, 0.f, 0.f, 0.f}; o[jd] = z; }
  float mold[4] = {-1e30f, -1e30f, -1e30f, -1e30f};
  float lst[4] = {0.f, 0.f, 0.f, 0.f};

  const int NKT = 2 * qb + 2;
  for (int kt = 0; kt < NKT; ++kt) {
    __syncthreads();
    const u16* kb = &kbf[(size_t)(kt * 64) * (NKV_ * HD_) + kvh * HD_];
    const u16* vb = &vbf[(size_t)(kt * 64) * (NKV_ * HD_) + kvh * HD_];
#pragma unroll
    for (int p = 0; p < 2; ++p) {           // K: 64 rows x 256B, 1024 chunks
      int u = t + 512 * p;
      int r = u >> 4, c8 = u & 15;
      *(bf16x8*)&Ks[r * 136 + c8 * 8] =
          *(const bf16x8*)&kb[(size_t)r * (NKV_ * HD_) + c8 * 8];
    }
#pragma unroll
    for (int p = 0; p < 2; ++p) {           // V: transpose + block rotation
      int u = t + 512 * p;
      int d = u & 127, bb = u >> 7;
      const u16* vsrc = &vb[(size_t)(bb * 8) * (NKV_ * HD_) + d];
      short vv[8];
#pragma unroll
      for (int j = 0; j < 8; ++j) vv[j] = (short)vsrc[(size_t)j * (NKV_ * HD_)];
      bf16x8 pk = { vv[0], vv[1], vv[2], vv[3], vv[4], vv[5], vv[6], vv[7] };
      *(bf16x8*)&Vt[d * 64 + ((bb + d) & 7) * 8] = pk;
    }
    __syncthreads();

    f32x4 sa[4];
#pragma unroll
    for (int jn = 0; jn < 4; ++jn) { f32x4 z = {0.f, 0.f, 0.f, 0.f}; sa[jn] = z; }
#pragma unroll
    for (int s = 0; s < 4; ++s) {
#pragma unroll
      for (int jn = 0; jn < 4; ++jn) {
        bf16x8 kf = *(const bf16x8*)&Ks[(16 * jn + L) * 136 + 32 * s + 8 * Q4];
        sa[jn] = __builtin_amdgcn_mfma_f32_16x16x32_bf16(qf[s], kf, sa[jn], 0, 0, 0);
      }
    }

    const int gq0 = qs0 + 16 * wave + 4 * Q4;
    const int gk0 = kt * 64 + L;
    float rmax[4];
#pragma unroll
    for (int r = 0; r < 4; ++r) {
#pragma unroll
      for (int jn = 0; jn < 4; ++jn)
        if (gk0 + 16 * jn > gq0 + r) sa[jn][r] = -1e30f;
      rmax[r] = fmaxf(fmaxf(sa[0][r], sa[1][r]), fmaxf(sa[2][r], sa[3][r]));
    }
#pragma unroll
    for (int m = 1; m < 16; m <<= 1) {
#pragma unroll
      for (int r = 0; r < 4; ++r) rmax[r] = fmaxf(rmax[r], __shfl_xor(rmax[r], m));
    }
    float p_[4][4], rsum[4], alpha[4];
#pragma unroll
    for (int r = 0; r < 4; ++r) {
      float mnew = fmaxf(mold[r], rmax[r]);
      alpha[r] = __expf(mold[r] - mnew);
#pragma unroll
      for (int jn = 0; jn < 4; ++jn) p_[jn][r] = __expf(sa[jn][r] - mnew);
      rsum[r] = (p_[0][r] + p_[1][r]) + (p_[2][r] + p_[3][r]);
      mold[r] = mnew;
    }
#pragma unroll
    for (int m = 1; m < 16; m <<= 1) {
#pragma unroll
      for (int r = 0; r < 4; ++r) rsum[r] += __shfl_xor(rsum[r], m);
    }
#pragma unroll
    for (int r = 0; r < 4; ++r) lst[r] = lst[r] * alpha[r] + rsum[r];
#pragma unroll
    for (int jd = 0; jd < 8; ++jd)
#pragma unroll
      for (int r = 0; r < 4; ++r) o[jd][r] *= alpha[r];

#pragma unroll
    for (int r = 0; r < 4; ++r)
#pragma unroll
      for (int jn = 0; jn < 4; ++jn)
        Psw[(4 * Q4 + r) * 72 + 16 * jn + L] = (u16)f2bf(p_[jn][r]);
    asm volatile("s_waitcnt lgkmcnt(0)" ::: "memory");

#pragma unroll
    for (int s2 = 0; s2 < 2; ++s2) {
      bf16x8 pa = *(const bf16x8*)&Psw[L * 72 + 32 * s2 + 8 * Q4];
#pragma unroll
      for (int jd = 0; jd < 8; ++jd) {
        bf16x8 vf = *(const bf16x8*)&Vt[(16 * jd + L) * 64 + ((4 * s2 + Q4 + L) & 7) * 8];
        o[jd] = __builtin_amdgcn_mfma_f32_16x16x32_bf16(pa, vf, o[jd], 0, 0, 0);
      }
    }
  }

  float inv[4];
#pragma unroll
  for (int r = 0; r < 4; ++r) inv[r] = 1.0f / lst[r];
#pragma unroll
  for (int r = 0; r < 4; ++r) {
    u16* dst = &ao[(size_t)(qs0 + 16 * wave + 4 * Q4 + r) * D_DIM + h * HD_ + L];
#pragma unroll
    for (int jd = 0; jd < 8; ++jd) dst[16 * jd] = (u16)f2bf(o[jd][r] * inv[r]);
  }
}

// ===========================================================================
// Fallback path (round-2 kernels, verified) for small ws_size
// ===========================================================================
#define LDA 40
__global__ __launch_bounds__(256) void gemm_bt(const float* __restrict__ A,
                                               const float* __restrict__ W,
                                               float* __restrict__ C, int N) {
  __shared__ short As[128 * LDA];
  __shared__ short Bs[128 * LDA];
  const int t = threadIdx.x;
  const int lane = t & 63;
  const int wave = t >> 6;
  const int wm = (wave >> 1) * 64;
  const int wn = (wave & 1) * 64;
  const int quad = lane >> 4;
  const int l15 = lane & 15;
  const int bm = blockIdx.y * 128;
  const int bn = blockIdx.x * 128;
  f32x4 acc[4][4];
#pragma unroll
  for (int i = 0; i < 4; ++i)
#pragma unroll
    for (int j = 0; j < 4; ++j) { f32x4 z = {0.f, 0.f, 0.f, 0.f}; acc[i][j] = z; }
  for (int k0 = 0; k0 < GK; k0 += 32) {
    __syncthreads();
#pragma unroll
    for (int p = 0; p < 4; ++p) {
      int idx = p * 256 + t;
      int row = idx >> 3;
      int c4 = (idx & 7) * 4;
      const float4 av = *(const float4*)&A[(size_t)(bm + row) * GK + k0 + c4];
      const float4 wv = *(const float4*)&W[(size_t)(bn + row) * GK + k0 + c4];
      s16x4 a4 = { f2bf(av.x), f2bf(av.y), f2bf(av.z), f2bf(av.w) };
      s16x4 w4 = { f2bf(wv.x), f2bf(wv.y), f2bf(wv.z), f2bf(wv.w) };
      *(s16x4*)&As[row * LDA + c4] = a4;
      *(s16x4*)&Bs[row * LDA + c4] = w4;
    }
    __syncthreads();
    bf16x8 af[4], bfr[4];
#pragma unroll
    for (int i = 0; i < 4; ++i) {
      af[i]  = *(const bf16x8*)&As[(wm + i * 16 + l15) * LDA + quad * 8];
      bfr[i] = *(const bf16x8*)&Bs[(wn + i * 16 + l15) * LDA + quad * 8];
    }
#pragma unroll
    for (int i = 0; i < 4; ++i)
#pragma unroll
      for (int j = 0; j < 4; ++j)
        acc[i][j] = __builtin_amdgcn_mfma_f32_16x16x32_bf16(af[i], bfr[j], acc[i][j], 0, 0, 0);
  }
#pragma unroll
  for (int i = 0; i < 4; ++i) {
    int r0 = bm + wm + i * 16 + quad * 4;
#pragma unroll
    for (int j = 0; j < 4; ++j) {
      int c = bn + wn + j * 16 + l15;
#pragma unroll
      for (int r = 0; r < 4; ++r) C[(size_t)(r0 + r) * N + c] = acc[i][j][r];
    }
  }
}

__global__ __launch_bounds__(256) void rope_kernel(float* __restrict__ xq,
                                                   const float* __restrict__ xk,
                                                   float* __restrict__ cko,
                                                   const float* __restrict__ fc,
                                                   const float* __restrict__ fs) {
  int i = blockIdx.x * 256 + threadIdx.x;
  const int NQP = S_LEN * NH_ * (HD_ / 2);
  if (i < NQP) {
    int s = i >> 11; int rem = i & 2047; int p = rem & 63;
    float c = fc[s * 64 + p], sn = fs[s * 64 + p];
    float2 v = *(const float2*)&xq[(size_t)s * D_DIM + 2 * rem];
    *(float2*)&xq[(size_t)s * D_DIM + 2 * rem] =
        make_float2(v.x * c - v.y * sn, v.x * sn + v.y * c);
  } else {
    int j = i - NQP; int s = j >> 9; int rem = j & 511; int p = rem & 63;
    float c = fc[s * 64 + p], sn = fs[s * 64 + p];
    float2 v = *(const float2*)&xk[(size_t)s * (NKV_ * HD_) + 2 * rem];
    *(float2*)&cko[(size_t)s * (NKV_ * HD_) + 2 * rem] =
        make_float2(v.x * c - v.y * sn, v.x * sn + v.y * c);
  }
}

__global__ __launch_bounds__(256, 3) void attn_mfma(const float* __restrict__ xq,
                                                    const float* __restrict__ ck,
                                                    const float* __restrict__ cv,
                                                    float* __restrict__ outp) {
  __shared__ __align__(16) short Ks[64 * 136];
  __shared__ __align__(16) short Vt[128 * 64];
  __shared__ __align__(16) short Ps[4 * 16 * 72];
  const int t = threadIdx.x;
  const int wave = t >> 6;
  const int lane = t & 63;
  const int Q4 = lane >> 4;
  const int L = lane & 15;
  const int h = blockIdx.y;
  const int qb = 31 - (int)blockIdx.x;
  const int kvh = h >> 2;
  const int qs0 = qb * 64;
  const float scale = 0.08838834764831845f;
  short* Psw = &Ps[wave * 16 * 72];
  bf16x8 qf[4];
  {
    const float* qbase = &xq[(size_t)(qs0 + 16 * wave + L) * D_DIM + h * HD_ + 8 * Q4];
#pragma unroll
    for (int s = 0; s < 4; ++s) {
      float4 a = *(const float4*)&qbase[32 * s];
      float4 b = *(const float4*)&qbase[32 * s + 4];
      bf16x8 q8 = { f2bf(a.x * scale), f2bf(a.y * scale), f2bf(a.z * scale), f2bf(a.w * scale),
                    f2bf(b.x * scale), f2bf(b.y * scale), f2bf(b.z * scale), f2bf(b.w * scale) };
      qf[s] = q8;
    }
  }
  f32x4 o[8];
#pragma unroll
  for (int jd = 0; jd < 8; ++jd) { f32x4 z = {0.f, 0.f, 0.f, 0.f}; o[jd] = z; }
  float mold[4] = {-1e30f, -1e30f, -1e30f, -1e30f};
  float lst[4] = {0.f, 0.f, 0.f, 0.f};
  for (int kt = 0; kt <= qb; ++kt) {
    __syncthreads();
    const float* ckb = &ck[(size_t)(kt * 64) * (NKV_ * HD_) + kvh * HD_];
    const float* cvb = &cv[(size_t)(kt * 64) * (NKV_ * HD_) + kvh * HD_];
#pragma unroll
    for (int p = 0; p < 8; ++p) {
      int i = t + 256 * p;
      int r = i >> 5, c4 = (i & 31) * 4;
      float4 v = *(const float4*)&ckb[(size_t)r * (NKV_ * HD_) + c4];
      s16x4 k4 = { f2bf(v.x), f2bf(v.y), f2bf(v.z), f2bf(v.w) };
      *(s16x4*)&Ks[r * 136 + c4] = k4;
    }
#pragma unroll
    for (int p = 0; p < 4; ++p) {
      int u = t + 256 * p;
      int d = u & 127, bb = u >> 7;
      float vv[8];
#pragma unroll
      for (int j = 0; j < 8; ++j) vv[j] = cvb[(size_t)(bb * 8 + j) * (NKV_ * HD_) + d];
      bf16x8 pk = { f2bf(vv[0]), f2bf(vv[1]), f2bf(vv[2]), f2bf(vv[3]),
                    f2bf(vv[4]), f2bf(vv[5]), f2bf(vv[6]), f2bf(vv[7]) };
      *(bf16x8*)&Vt[d * 64 + ((bb + d) & 7) * 8] = pk;
    }
    __syncthreads();
    f32x4 sa[4];
#pragma unroll
    for (int jn = 0; jn < 4; ++jn) { f32x4 z = {0.f, 0.f, 0.f, 0.f}; sa[jn] = z; }
#pragma unroll
    for (int s = 0; s < 4; ++s) {
#pragma unroll
      for (int jn = 0; jn < 4; ++jn) {
        bf16x8 kf = *(const bf16x8*)&Ks[(16 * jn + L) * 136 + 32 * s + 8 * Q4];
        sa[jn] = __builtin_amdgcn_mfma_f32_16x16x32_bf16(qf[s], kf, sa[jn], 0, 0, 0);
      }
    }
    const int gq0 = qs0 + 16 * wave + 4 * Q4;
    const int gk0 = kt * 64 + L;
    float rmax[4];
#pragma unroll
    for (int r = 0; r < 4; ++r) {
#pragma unroll
      for (int jn = 0; jn < 4; ++jn)
        if (gk0 + 16 * jn > gq0 + r) sa[jn][r] = -1e30f;
      rmax[r] = fmaxf(fmaxf(sa[0][r], sa[1][r]), fmaxf(sa[2][r], sa[3][r]));
    }
#pragma unroll
    for (int m = 1; m < 16; m <<= 1) {
#pragma unroll
      for (int r = 0; r < 4; ++r) rmax[r] = fmaxf(rmax[r], __shfl_xor(rmax[r], m));
    }
    float p_[4][4], rsum[4], alpha[4];
#pragma unroll
    for (int r = 0; r < 4; ++r) {
      float mnew = fmaxf(mold[r], rmax[r]);
      alpha[r] = __expf(mold[r] - mnew);
#pragma unroll
      for (int jn = 0; jn < 4; ++jn) p_[jn][r] = __expf(sa[jn][r] - mnew);
      rsum[r] = (p_[0][r] + p_[1][r]) + (p_[2][r] + p_[3][r]);
      mold[r] = mnew;
    }
#pragma unroll
    for (int m = 1; m < 16; m <<= 1) {
#pragma unroll
      for (int r = 0; r < 4; ++r) rsum[r] += __shfl_xor(rsum[r], m);
    }
#pragma unroll
    for (int r = 0; r < 4; ++r) lst[r] = lst[r] * alpha[r] + rsum[r];
#pragma unroll
    for (int jd = 0; jd < 8; ++jd)
#pragma unroll
      for (int r = 0; r < 4; ++r) o[jd][r] *= alpha[r];
#pragma unroll
    for (int r = 0; r < 4; ++r)
#pragma unroll
      for (int jn = 0; jn < 4; ++jn)
        Psw[(4 * Q4 + r) * 72 + 16 * jn + L] = f2bf(p_[jn][r]);
    asm volatile("s_waitcnt lgkmcnt(0)" ::: "memory");
#pragma unroll
    for (int s2 = 0; s2 < 2; ++s2) {
      bf16x8 pa = *(const bf16x8*)&Psw[L * 72 + 32 * s2 + 8 * Q4];
#pragma unroll
      for (int jd = 0; jd < 8; ++jd) {
        bf16x8 vf = *(const bf16x8*)&Vt[(16 * jd + L) * 64 + ((4 * s2 + Q4 + L) & 7) * 8];
        o[jd] = __builtin_amdgcn_mfma_f32_16x16x32_bf16(pa, vf, o[jd], 0, 0, 0);
      }
    }
  }
  float inv[4];
#pragma unroll
  for (int r = 0; r < 4; ++r) inv[r] = 1.0f / lst[r];
#pragma unroll
  for (int r = 0; r < 4; ++r) {
    float* dst = &outp[(size_t)(qs0 + 16 * wave + 4 * Q4 + r) * D_DIM + h * HD_ + L];
#pragma unroll
    for (int jd = 0; jd < 8; ++jd) dst[16 * jd] = o[jd][r] * inv[r];
  }
}

// ---------------------------------------------------------------------------
// Inputs: 0:x 1:fc 2:fs 3:mask(unused) 4:idx(unused) 5:ck0 6:cv0 7:wq 8:wk
// 9:wv 10:wo. d_out = [out | cache_k | cache_v].
// Fast path ws (bytes): x_bf 16.8M | wqkv 50.3M (wo reuses) | q_bf 16.8M |
// k_bf 4.2M | v_bf 4.2M | ao_bf 16.8M = 109,051,904 B. Else round-2 path.
// ---------------------------------------------------------------------------
extern "C" void kernel_launch(void* const* d_in, const int* in_sizes, int n_in,
                              void* d_out, int out_size, void* d_ws, size_t ws_size,
                              hipStream_t stream) {
  (void)in_sizes; (void)n_in; (void)out_size;
  const float* x  = (const float*)d_in[0];
  const float* fc = (const float*)d_in[1];
  const float* fs = (const float*)d_in[2];
  const float* wq = (const float*)d_in[7];
  const float* wk = (const float*)d_in[8];
  const float* wv = (const float*)d_in[9];
  const float* wo = (const float*)d_in[10];
  float* outp = (float*)d_out;
  float* ck = outp + (size_t)S_LEN * D_DIM;
  float* cv = ck + (size_t)S_LEN * NKV_ * HD_;

  if (ws_size >= 109051904ull) {
    u16* x_bf = (u16*)d_ws;                       //  8,388,608 elems
    u16* wqkv = x_bf + 8388608;                   // 25,165,824 elems
    u16* q_bf = wqkv + 25165824;                  //  8,388,608
    u16* k_bf = q_bf + 8388608;                   //  2,097,152
    u16* v_bf = k_bf + 2097152;                   //  2,097,152
    u16* ao_bf = v_bf + 2097152;                  //  8,388,608
    u16* wo_bf = wqkv;                            // reuse after qkv gemm

    cvt_bf16<<<4096, 256, 0, stream>>>(x, x_bf, 1048576);
    cvt_bf16<<<8192, 256, 0, stream>>>(wq, wqkv, 2097152);
    cvt_bf16<<<2048, 256, 0, stream>>>(wk, wqkv + 16777216, 524288);
    cvt_bf16<<<2048, 256, 0, stream>>>(wv, wqkv + 20971520, 524288);
    gemm8<1><<<dim3(24, 8), 512, 0, stream>>>(x_bf, wqkv, nullptr, q_bf,
                                              k_bf, v_bf, ck, cv, fc, fs, 6144);
    cvt_bf16<<<8192, 256, 0, stream>>>(wo, wo_bf, 2097152);
    attn_bf<<<dim3(16, 32), 512, 0, stream>>>(q_bf, k_bf, v_bf, ao_bf);
    gemm8<0><<<dim3(16, 8), 512, 0, stream>>>(ao_bf, wo_bf, outp, nullptr,
                                              nullptr, nullptr, nullptr,
                                              nullptr, fc, fs, 4096);
  } else {
    float* xq = (float*)d_ws;
    float* xk = xq + (size_t)S_LEN * D_DIM;
    dim3 blk(256);
    gemm_bt<<<dim3(32, 16), blk, 0, stream>>>(x, wq, xq, 4096);
    gemm_bt<<<dim3(8, 16),  blk, 0, stream>>>(x, wk, xk, 1024);
    gemm_bt<<<dim3(8, 16),  blk, 0, stream>>>(x, wv, cv, 1024);
    rope_kernel<<<20480, 256, 0, stream>>>(xq, xk, ck, fc, fs);
    attn_mfma<<<dim3(32, 32), 512 / 2, 0, stream>>>(xq, ck, cv, xq);
    gemm_bt<<<dim3(32, 16), blk, 0, stream>>>(xq, wo, outp, 4096);
  }
}

// Round 3
// 631.103 us; speedup vs baseline: 1.0845x; 1.0238x over previous
//
#include <hip/hip_runtime.h>
#include <cstdint>

#define S_LEN 2048
#define D_DIM 4096
#define NH_ 32
#define NKV_ 8
#define HD_ 128
#define GK 4096

typedef unsigned short u16;
typedef __attribute__((ext_vector_type(4))) float f32x4;
typedef __attribute__((ext_vector_type(8))) short bf16x8;
typedef __attribute__((ext_vector_type(4))) short s16x4;

__device__ __forceinline__ short f2bf(float f) {
  union { float f; unsigned int u; } v; v.f = f;
  unsigned int r = v.u + 0x7fffu + ((v.u >> 16) & 1u);
  return (short)(r >> 16);
}

__device__ __forceinline__ void glds16(const void* g, void* l) {
  __builtin_amdgcn_global_load_lds(
      (const __attribute__((address_space(1))) void*)g,
      (__attribute__((address_space(3))) void*)l, 16, 0, 0);
}

// ---------------------------------------------------------------------------
// fp32 -> bf16 convert, 8 elems/thread
// ---------------------------------------------------------------------------
__global__ __launch_bounds__(256) void cvt_bf16(const float* __restrict__ src,
                                                u16* __restrict__ dst, int n8) {
  int i = blockIdx.x * 256 + threadIdx.x;
  if (i < n8) {
    float4 a = *(const float4*)&src[(size_t)i * 8];
    float4 b = *(const float4*)&src[(size_t)i * 8 + 4];
    bf16x8 o = { f2bf(a.x), f2bf(a.y), f2bf(a.z), f2bf(a.w),
                 f2bf(b.x), f2bf(b.y), f2bf(b.z), f2bf(b.w) };
    *(bf16x8*)&dst[(size_t)i * 8] = o;
  }
}

// ---------------------------------------------------------------------------
// 256 x (NI*64) 4-phase bf16 GEMM.  C[M x N] = A[M x 4096] * W[N x 4096]^T.
// 512 thr / 8 waves (2M x 4N), wave tile 128 x (NI*16), BK=64, double-buffered
// LDS, XOR block swizzle LDS[r][blk] = G[r][blk ^ (r&7)].
// Phases (mh,s): reads 4 af always + NI bw on ph0/ph2 (even distribution);
// ph0 stages A(kt+1), ph3 stages B(kt+2), counted s_waitcnt vmcnt(NI) once
// per K-tile keeps B(kt+2)'s NI loads in flight.
// Grid z = split-K slices (ktPer K-tiles each).
// NI=3: BN=192 (QKV grid 32x8 = 256 wg).  NI=4: BN=256 (WO 16x8x2 = 256 wg).
// MODE 0: fp32 C store (ATOMIC: unsafeAtomicAdd for split-K).
// MODE 1: fused QKV epilogue (N=6144) with RoPE.
// ---------------------------------------------------------------------------
template <int MODE, int NI, int ATOMIC>
__global__ __launch_bounds__(512, 2) void gemm8(const u16* __restrict__ Amat,
                                                const u16* __restrict__ W,
                                                float* __restrict__ C,
                                                u16* __restrict__ qbf,
                                                u16* __restrict__ kbf,
                                                u16* __restrict__ vbf,
                                                float* __restrict__ cko,
                                                float* __restrict__ cvo,
                                                const float* __restrict__ fc,
                                                const float* __restrict__ fs,
                                                int N, int ktPer) {
  __shared__ __align__(16) u16 As[2][16384];      // 2 x 32 KB
  __shared__ __align__(16) u16 Bs[2][NI * 4096];  // 2 x NI*8 KB
  const int t = threadIdx.x;
  const int lane = t & 63;
  const int wave = t >> 6;        // 0..7
  const int wr = wave >> 2;       // 0..1  M half
  const int wc = wave & 3;        // 0..3  N quarter
  const int quad = lane >> 4;
  const int L = lane & 15;
  const int bm = blockIdx.y * 256;
  const int bn = blockIdx.x * (NI * 64);
  const int dr = lane >> 3;       // row within 8-row chunk
  const int cb = lane & 7;        // 16B block within 128B row
  const int cbs = cb ^ dr;        // pre-swizzled source block
  const int kt0 = blockIdx.z * ktPer;
  const int ktN = kt0 + ktPer;

  auto stageA = [&](int tile) {   // 256 rows x 64 k = 32 KB, 4 glds/thread
    u16* dst = &As[tile & 1][0];
    const int k0 = tile << 6;
#pragma unroll
    for (int c = 0; c < 4; ++c) {
      const int chunk = wave * 4 + c;        // 0..31, 8 rows each
      const int row = chunk * 8 + dr;
      glds16(&Amat[(size_t)(bm + row) * GK + k0 + cbs * 8], &dst[chunk * 512]);
    }
  };
  auto stageB = [&](int tile) {   // NI*64 rows x 64 k, NI glds/thread
    u16* dst = &Bs[tile & 1][0];
    const int k0 = tile << 6;
#pragma unroll
    for (int c = 0; c < NI; ++c) {
      const int chunk = wave * NI + c;       // 0..8*NI-1
      const int row = chunk * 8 + dr;
      glds16(&W[(size_t)(bn + row) * GK + k0 + cbs * 8], &dst[chunk * 512]);
    }
  };

  f32x4 acc[8][NI];
#pragma unroll
  for (int i = 0; i < 8; ++i)
#pragma unroll
    for (int j = 0; j < NI; ++j) { f32x4 z = {0.f, 0.f, 0.f, 0.f}; acc[i][j] = z; }

  // prologue: tile kt0 complete, B(kt0+1) in flight (A(kt0+1) staged in ph0)
  stageB(kt0); stageA(kt0); stageB(kt0 + 1);
  if constexpr (NI == 3) asm volatile("s_waitcnt vmcnt(3)" ::: "memory");
  else                   asm volatile("s_waitcnt vmcnt(4)" ::: "memory");
  __builtin_amdgcn_s_barrier();
  __builtin_amdgcn_sched_barrier(0);

  bf16x8 af[4], bw[NI];
  const int arow = wr * 128;
  const int brow = wc * (NI * 16);

  for (int kt = kt0; kt < ktN; ++kt) {
    const u16* as = &As[kt & 1][0];
    const u16* bs = &Bs[kt & 1][0];
#pragma unroll
    for (int ph = 0; ph < 4; ++ph) {
      const int mh = ph & 1;      // ph0:(m0,s0) ph1:(m1,s0) ph2:(m0,s1) ph3:(m1,s1)
      const int s = ph >> 1;
#pragma unroll
      for (int i = 0; i < 4; ++i)
        af[i] = *(const bf16x8*)&as[(arow + mh * 64 + i * 16 + L) * 64 +
                                     (((s * 4 + quad) ^ (L & 7)) * 8)];
      if (ph == 0 || ph == 2) {
#pragma unroll
        for (int j = 0; j < NI; ++j)
          bw[j] = *(const bf16x8*)&bs[(brow + j * 16 + L) * 64 +
                                       (((s * 4 + quad) ^ (L & 7)) * 8)];
      }
      if (ph == 0 && kt + 1 < ktN) stageA(kt + 1);
      if (ph == 3 && kt + 2 < ktN) stageB(kt + 2);
      __builtin_amdgcn_s_barrier();
      asm volatile("s_waitcnt lgkmcnt(0)" ::: "memory");
      __builtin_amdgcn_sched_barrier(0);
      __builtin_amdgcn_s_setprio(1);
#pragma unroll
      for (int i = 0; i < 4; ++i)
#pragma unroll
        for (int j = 0; j < NI; ++j)
          acc[mh * 4 + i][j] = __builtin_amdgcn_mfma_f32_16x16x32_bf16(
              af[i], bw[j], acc[mh * 4 + i][j], 0, 0, 0);
      __builtin_amdgcn_s_setprio(0);
      if (ph == 3) {
        if (kt + 2 < ktN) {
          if constexpr (NI == 3) asm volatile("s_waitcnt vmcnt(3)" ::: "memory");
          else                   asm volatile("s_waitcnt vmcnt(4)" ::: "memory");
        } else {
          asm volatile("s_waitcnt vmcnt(0)" ::: "memory");
        }
      }
      __builtin_amdgcn_s_barrier();
      __builtin_amdgcn_sched_barrier(0);
    }
  }

  if (MODE == 0) {
#pragma unroll
    for (int mi = 0; mi < 8; ++mi) {
      int r0 = bm + wr * 128 + mi * 16 + quad * 4;
#pragma unroll
      for (int ni = 0; ni < NI; ++ni) {
        int c = bn + wc * (NI * 16) + ni * 16 + L;
#pragma unroll
        for (int r = 0; r < 4; ++r) {
          if (ATOMIC) unsafeAtomicAdd(&C[(size_t)(r0 + r) * N + c], acc[mi][ni][r]);
          else        C[(size_t)(r0 + r) * N + c] = acc[mi][ni][r];
        }
      }
    }
  } else {
    const float scale = 0.08838834764831845f;  // 1/sqrt(128)
#pragma unroll
    for (int mi = 0; mi < 8; ++mi) {
#pragma unroll
      for (int ni = 0; ni < NI; ++ni) {
        int c = bn + wc * (NI * 16) + ni * 16 + L;
#pragma unroll
        for (int r = 0; r < 4; ++r) {
          int srow = bm + wr * 128 + mi * 16 + 4 * quad + r;
          float v = acc[mi][ni][r];
          float partner = __shfl_xor(v, 1);  // all lanes, before branch
          if (c < 4096) {
            int p = (c >> 1) & 63;
            float co = fc[srow * 64 + p], si = fs[srow * 64 + p];
            float out = (c & 1) ? partner * si + v * co : v * co - partner * si;
            qbf[(size_t)srow * 4096 + c] = (u16)f2bf(out * scale);
          } else if (c < 5120) {
            int p = (c >> 1) & 63;
            float co = fc[srow * 64 + p], si = fs[srow * 64 + p];
            float out = (c & 1) ? partner * si + v * co : v * co - partner * si;
            int cc = c - 4096;
            cko[(size_t)srow * 1024 + cc] = out;
            kbf[(size_t)srow * 1024 + cc] = (u16)f2bf(out);
          } else {
            int cc = c - 5120;
            cvo[(size_t)srow * 1024 + cc] = v;
            vbf[(size_t)srow * 1024 + cc] = (u16)f2bf(v);
          }
        }
      }
    }
  }
}

// ---------------------------------------------------------------------------
// MFMA flash attention, bf16 in/out. 8 waves / 512 thr, QBLK=128/block.
// Per wave: 16 q-rows, 64-k tiles, C-layout softmax, P->LDS, Vt rotated-block
// transpose. Waves 0-3 see one fully-masked diagonal tile: safe (mold finite
// after kt=0 since col 0 is unmasked for every row).
// ---------------------------------------------------------------------------
__global__ __launch_bounds__(512, 2) void attn_bf(const u16* __restrict__ qbf,
                                                  const u16* __restrict__ kbf,
                                                  const u16* __restrict__ vbf,
                                                  u16* __restrict__ ao) {
  __shared__ __align__(16) u16 Ks[64 * 136];
  __shared__ __align__(16) u16 Vt[128 * 64];
  __shared__ __align__(16) u16 Ps[8 * 16 * 72];
  const int t = threadIdx.x;
  const int wave = t >> 6;          // 0..7
  const int lane = t & 63;
  const int Q4 = lane >> 4;
  const int L = lane & 15;
  const int h = blockIdx.y;
  const int qb = 15 - (int)blockIdx.x;
  const int kvh = h >> 2;
  const int qs0 = qb * 128;
  u16* Psw = &Ps[wave * 16 * 72];

  bf16x8 qf[4];
  {
    const u16* qbase = &qbf[(size_t)(qs0 + 16 * wave + L) * D_DIM + h * HD_ + 8 * Q4];
#pragma unroll
    for (int s = 0; s < 4; ++s) qf[s] = *(const bf16x8*)&qbase[32 * s];
  }

  f32x4 o[8];
#pragma unroll
  for (int jd = 0; jd < 8; ++jd) { f32x4 z = {0.f, 0.f, 0.f, 0.f}; o[jd] = z; }
  float mold[4] = {-1e30f, -1e30f, -1e30f, -1e30f};
  float lst[4] = {0.f, 0.f, 0.f, 0.f};

  const int NKT = 2 * qb + 2;
  for (int kt = 0; kt < NKT; ++kt) {
    __syncthreads();
    const u16* kb = &kbf[(size_t)(kt * 64) * (NKV_ * HD_) + kvh * HD_];
    const u16* vb = &vbf[(size_t)(kt * 64) * (NKV_ * HD_) + kvh * HD_];
#pragma unroll
    for (int p = 0; p < 2; ++p) {           // K: 64 rows x 256B, 1024 chunks
      int u = t + 512 * p;
      int r = u >> 4, c8 = u & 15;
      *(bf16x8*)&Ks[r * 136 + c8 * 8] =
          *(const bf16x8*)&kb[(size_t)r * (NKV_ * HD_) + c8 * 8];
    }
#pragma unroll
    for (int p = 0; p < 2; ++p) {           // V: transpose + block rotation
      int u = t + 512 * p;
      int d = u & 127, bb = u >> 7;
      const u16* vsrc = &vb[(size_t)(bb * 8) * (NKV_ * HD_) + d];
      short vv[8];
#pragma unroll
      for (int j = 0; j < 8; ++j) vv[j] = (short)vsrc[(size_t)j * (NKV_ * HD_)];
      bf16x8 pk = { vv[0], vv[1], vv[2], vv[3], vv[4], vv[5], vv[6], vv[7] };
      *(bf16x8*)&Vt[d * 64 + ((bb + d) & 7) * 8] = pk;
    }
    __syncthreads();

    f32x4 sa[4];
#pragma unroll
    for (int jn = 0; jn < 4; ++jn) { f32x4 z = {0.f, 0.f, 0.f, 0.f}; sa[jn] = z; }
#pragma unroll
    for (int s = 0; s < 4; ++s) {
#pragma unroll
      for (int jn = 0; jn < 4; ++jn) {
        bf16x8 kf = *(const bf16x8*)&Ks[(16 * jn + L) * 136 + 32 * s + 8 * Q4];
        sa[jn] = __builtin_amdgcn_mfma_f32_16x16x32_bf16(qf[s], kf, sa[jn], 0, 0, 0);
      }
    }

    const int gq0 = qs0 + 16 * wave + 4 * Q4;
    const int gk0 = kt * 64 + L;
    float rmax[4];
#pragma unroll
    for (int r = 0; r < 4; ++r) {
#pragma unroll
      for (int jn = 0; jn < 4; ++jn)
        if (gk0 + 16 * jn > gq0 + r) sa[jn][r] = -1e30f;
      rmax[r] = fmaxf(fmaxf(sa[0][r], sa[1][r]), fmaxf(sa[2][r], sa[3][r]));
    }
#pragma unroll
    for (int m = 1; m < 16; m <<= 1) {
#pragma unroll
      for (int r = 0; r < 4; ++r) rmax[r] = fmaxf(rmax[r], __shfl_xor(rmax[r], m));
    }
    float p_[4][4], rsum[4], alpha[4];
#pragma unroll
    for (int r = 0; r < 4; ++r) {
      float mnew = fmaxf(mold[r], rmax[r]);
      alpha[r] = __expf(mold[r] - mnew);
#pragma unroll
      for (int jn = 0; jn < 4; ++jn) p_[jn][r] = __expf(sa[jn][r] - mnew);
      rsum[r] = (p_[0][r] + p_[1][r]) + (p_[2][r] + p_[3][r]);
      mold[r] = mnew;
    }
#pragma unroll
    for (int m = 1; m < 16; m <<= 1) {
#pragma unroll
      for (int r = 0; r < 4; ++r) rsum[r] += __shfl_xor(rsum[r], m);
    }
#pragma unroll
    for (int r = 0; r < 4; ++r) lst[r] = lst[r] * alpha[r] + rsum[r];
#pragma unroll
    for (int jd = 0; jd < 8; ++jd)
#pragma unroll
      for (int r = 0; r < 4; ++r) o[jd][r] *= alpha[r];

#pragma unroll
    for (int r = 0; r < 4; ++r)
#pragma unroll
      for (int jn = 0; jn < 4; ++jn)
        Psw[(4 * Q4 + r) * 72 + 16 * jn + L] = (u16)f2bf(p_[jn][r]);
    asm volatile("s_waitcnt lgkmcnt(0)" ::: "memory");

#pragma unroll
    for (int s2 = 0; s2 < 2; ++s2) {
      bf16x8 pa = *(const bf16x8*)&Psw[L * 72 + 32 * s2 + 8 * Q4];
#pragma unroll
      for (int jd = 0; jd < 8; ++jd) {
        bf16x8 vf = *(const bf16x8*)&Vt[(16 * jd + L) * 64 + ((4 * s2 + Q4 + L) & 7) * 8];
        o[jd] = __builtin_amdgcn_mfma_f32_16x16x32_bf16(pa, vf, o[jd], 0, 0, 0);
      }
    }
  }

  float inv[4];
#pragma unroll
  for (int r = 0; r < 4; ++r) inv[r] = 1.0f / lst[r];
#pragma unroll
  for (int r = 0; r < 4; ++r) {
    u16* dst = &ao[(size_t)(qs0 + 16 * wave + 4 * Q4 + r) * D_DIM + h * HD_ + L];
#pragma unroll
    for (int jd = 0; jd < 8; ++jd) dst[16 * jd] = (u16)f2bf(o[jd][r] * inv[r]);
  }
}

// ===========================================================================
// Fallback path (round-2 kernels, verified) for small ws_size
// ===========================================================================
#define LDA 40
__global__ __launch_bounds__(256) void gemm_bt(const float* __restrict__ A,
                                               const float* __restrict__ W,
                                               float* __restrict__ C, int N) {
  __shared__ short As[128 * LDA];
  __shared__ short Bs[128 * LDA];
  const int t = threadIdx.x;
  const int lane = t & 63;
  const int wave = t >> 6;
  const int wm = (wave >> 1) * 64;
  const int wn = (wave & 1) * 64;
  const int quad = lane >> 4;
  const int l15 = lane & 15;
  const int bm = blockIdx.y * 128;
  const int bn = blockIdx.x * 128;
  f32x4 acc[4][4];
#pragma unroll
  for (int i = 0; i < 4; ++i)
#pragma unroll
    for (int j = 0; j < 4; ++j) { f32x4 z = {0.f, 0.f, 0.f, 0.f}; acc[i][j] = z; }
  for (int k0 = 0; k0 < GK; k0 += 32) {
    __syncthreads();
#pragma unroll
    for (int p = 0; p < 4; ++p) {
      int idx = p * 256 + t;
      int row = idx >> 3;
      int c4 = (idx & 7) * 4;
      const float4 av = *(const float4*)&A[(size_t)(bm + row) * GK + k0 + c4];
      const float4 wv = *(const float4*)&W[(size_t)(bn + row) * GK + k0 + c4];
      s16x4 a4 = { f2bf(av.x), f2bf(av.y), f2bf(av.z), f2bf(av.w) };
      s16x4 w4 = { f2bf(wv.x), f2bf(wv.y), f2bf(wv.z), f2bf(wv.w) };
      *(s16x4*)&As[row * LDA + c4] = a4;
      *(s16x4*)&Bs[row * LDA + c4] = w4;
    }
    __syncthreads();
    bf16x8 af[4], bfr[4];
#pragma unroll
    for (int i = 0; i < 4; ++i) {
      af[i]  = *(const bf16x8*)&As[(wm + i * 16 + l15) * LDA + quad * 8];
      bfr[i] = *(const bf16x8*)&Bs[(wn + i * 16 + l15) * LDA + quad * 8];
    }
#pragma unroll
    for (int i = 0; i < 4; ++i)
#pragma unroll
      for (int j = 0; j < 4; ++j)
        acc[i][j] = __builtin_amdgcn_mfma_f32_16x16x32_bf16(af[i], bfr[j], acc[i][j], 0, 0, 0);
  }
#pragma unroll
  for (int i = 0; i < 4; ++i) {
    int r0 = bm + wm + i * 16 + quad * 4;
#pragma unroll
    for (int j = 0; j < 4; ++j) {
      int c = bn + wn + j * 16 + l15;
#pragma unroll
      for (int r = 0; r < 4; ++r) C[(size_t)(r0 + r) * N + c] = acc[i][j][r];
    }
  }
}

__global__ __launch_bounds__(256) void rope_kernel(float* __restrict__ xq,
                                                   const float* __restrict__ xk,
                                                   float* __restrict__ cko,
                                                   const float* __restrict__ fc,
                                                   const float* __restrict__ fs) {
  int i = blockIdx.x * 256 + threadIdx.x;
  const int NQP = S_LEN * NH_ * (HD_ / 2);
  if (i < NQP) {
    int s = i >> 11; int rem = i & 2047; int p = rem & 63;
    float c = fc[s * 64 + p], sn = fs[s * 64 + p];
    float2 v = *(const float2*)&xq[(size_t)s * D_DIM + 2 * rem];
    *(float2*)&xq[(size_t)s * D_DIM + 2 * rem] =
        make_float2(v.x * c - v.y * sn, v.x * sn + v.y * c);
  } else {
    int j = i - NQP; int s = j >> 9; int rem = j & 511; int p = rem & 63;
    float c = fc[s * 64 + p], sn = fs[s * 64 + p];
    float2 v = *(const float2*)&xk[(size_t)s * (NKV_ * HD_) + 2 * rem];
    *(float2*)&cko[(size_t)s * (NKV_ * HD_) + 2 * rem] =
        make_float2(v.x * c - v.y * sn, v.x * sn + v.y * c);
  }
}

__global__ __launch_bounds__(256, 3) void attn_mfma(const float* __restrict__ xq,
                                                    const float* __restrict__ ck,
                                                    const float* __restrict__ cv,
                                                    float* __restrict__ outp) {
  __shared__ __align__(16) short Ks[64 * 136];
  __shared__ __align__(16) short Vt[128 * 64];
  __shared__ __align__(16) short Ps[4 * 16 * 72];
  const int t = threadIdx.x;
  const int wave = t >> 6;
  const int lane = t & 63;
  const int Q4 = lane >> 4;
  const int L = lane & 15;
  const int h = blockIdx.y;
  const int qb = 31 - (int)blockIdx.x;
  const int kvh = h >> 2;
  const int qs0 = qb * 64;
  const float scale = 0.08838834764831845f;
  short* Psw = &Ps[wave * 16 * 72];
  bf16x8 qf[4];
  {
    const float* qbase = &xq[(size_t)(qs0 + 16 * wave + L) * D_DIM + h * HD_ + 8 * Q4];
#pragma unroll
    for (int s = 0; s < 4; ++s) {
      float4 a = *(const float4*)&qbase[32 * s];
      float4 b = *(const float4*)&qbase[32 * s + 4];
      bf16x8 q8 = { f2bf(a.x * scale), f2bf(a.y * scale), f2bf(a.z * scale), f2bf(a.w * scale),
                    f2bf(b.x * scale), f2bf(b.y * scale), f2bf(b.z * scale), f2bf(b.w * scale) };
      qf[s] = q8;
    }
  }
  f32x4 o[8];
#pragma unroll
  for (int jd = 0; jd < 8; ++jd) { f32x4 z = {0.f, 0.f, 0.f, 0.f}; o[jd] = z; }
  float mold[4] = {-1e30f, -1e30f, -1e30f, -1e30f};
  float lst[4] = {0.f, 0.f, 0.f, 0.f};
  for (int kt = 0; kt <= qb; ++kt) {
    __syncthreads();
    const float* ckb = &ck[(size_t)(kt * 64) * (NKV_ * HD_) + kvh * HD_];
    const float* cvb = &cv[(size_t)(kt * 64) * (NKV_ * HD_) + kvh * HD_];
#pragma unroll
    for (int p = 0; p < 8; ++p) {
      int i = t + 256 * p;
      int r = i >> 5, c4 = (i & 31) * 4;
      float4 v = *(const float4*)&ckb[(size_t)r * (NKV_ * HD_) + c4];
      s16x4 k4 = { f2bf(v.x), f2bf(v.y), f2bf(v.z), f2bf(v.w) };
      *(s16x4*)&Ks[r * 136 + c4] = k4;
    }
#pragma unroll
    for (int p = 0; p < 4; ++p) {
      int u = t + 256 * p;
      int d = u & 127, bb = u >> 7;
      float vv[8];
#pragma unroll
      for (int j = 0; j < 8; ++j) vv[j] = cvb[(size_t)(bb * 8 + j) * (NKV_ * HD_) + d];
      bf16x8 pk = { f2bf(vv[0]), f2bf(vv[1]), f2bf(vv[2]), f2bf(vv[3]),
                    f2bf(vv[4]), f2bf(vv[5]), f2bf(vv[6]), f2bf(vv[7]) };
      *(bf16x8*)&Vt[d * 64 + ((bb + d) & 7) * 8] = pk;
    }
    __syncthreads();
    f32x4 sa[4];
#pragma unroll
    for (int jn = 0; jn < 4; ++jn) { f32x4 z = {0.f, 0.f, 0.f, 0.f}; sa[jn] = z; }
#pragma unroll
    for (int s = 0; s < 4; ++s) {
#pragma unroll
      for (int jn = 0; jn < 4; ++jn) {
        bf16x8 kf = *(const bf16x8*)&Ks[(16 * jn + L) * 136 + 32 * s + 8 * Q4];
        sa[jn] = __builtin_amdgcn_mfma_f32_16x16x32_bf16(qf[s], kf, sa[jn], 0, 0, 0);
      }
    }
    const int gq0 = qs0 + 16 * wave + 4 * Q4;
    const int gk0 = kt * 64 + L;
    float rmax[4];
#pragma unroll
    for (int r = 0; r < 4; ++r) {
#pragma unroll
      for (int jn = 0; jn < 4; ++jn)
        if (gk0 + 16 * jn > gq0 + r) sa[jn][r] = -1e30f;
      rmax[r] = fmaxf(fmaxf(sa[0][r], sa[1][r]), fmaxf(sa[2][r], sa[3][r]));
    }
#pragma unroll
    for (int m = 1; m < 16; m <<= 1) {
#pragma unroll
      for (int r = 0; r < 4; ++r) rmax[r] = fmaxf(rmax[r], __shfl_xor(rmax[r], m));
    }
    float p_[4][4], rsum[4], alpha[4];
#pragma unroll
    for (int r = 0; r < 4; ++r) {
      float mnew = fmaxf(mold[r], rmax[r]);
      alpha[r] = __expf(mold[r] - mnew);
#pragma unroll
      for (int jn = 0; jn < 4; ++jn) p_[jn][r] = __expf(sa[jn][r] - mnew);
      rsum[r] = (p_[0][r] + p_[1][r]) + (p_[2][r] + p_[3][r]);
      mold[r] = mnew;
    }
#pragma unroll
    for (int m = 1; m < 16; m <<= 1) {
#pragma unroll
      for (int r = 0; r < 4; ++r) rsum[r] += __shfl_xor(rsum[r], m);
    }
#pragma unroll
    for (int r = 0; r < 4; ++r) lst[r] = lst[r] * alpha[r] + rsum[r];
#pragma unroll
    for (int jd = 0; jd < 8; ++jd)
#pragma unroll
      for (int r = 0; r < 4; ++r) o[jd][r] *= alpha[r];
#pragma unroll
    for (int r = 0; r < 4; ++r)
#pragma unroll
      for (int jn = 0; jn < 4; ++jn)
        Psw[(4 * Q4 + r) * 72 + 16 * jn + L] = f2bf(p_[jn][r]);
    asm volatile("s_waitcnt lgkmcnt(0)" ::: "memory");
#pragma unroll
    for (int s2 = 0; s2 < 2; ++s2) {
      bf16x8 pa = *(const bf16x8*)&Psw[L * 72 + 32 * s2 + 8 * Q4];
#pragma unroll
      for (int jd = 0; jd < 8; ++jd) {
        bf16x8 vf = *(const bf16x8*)&Vt[(16 * jd + L) * 64 + ((4 * s2 + Q4 + L) & 7) * 8];
        o[jd] = __builtin_amdgcn_mfma_f32_16x16x32_bf16(pa, vf, o[jd], 0, 0, 0);
      }
    }
  }
  float inv[4];
#pragma unroll
  for (int r = 0; r < 4; ++r) inv[r] = 1.0f / lst[r];
#pragma unroll
  for (int r = 0; r < 4; ++r) {
    float* dst = &outp[(size_t)(qs0 + 16 * wave + 4 * Q4 + r) * D_DIM + h * HD_ + L];
#pragma unroll
    for (int jd = 0; jd < 8; ++jd) dst[16 * jd] = o[jd][r] * inv[r];
  }
}

// ---------------------------------------------------------------------------
// Inputs: 0:x 1:fc 2:fs 3:mask(unused) 4:idx(unused) 5:ck0 6:cv0 7:wq 8:wk
// 9:wv 10:wo. d_out = [out | cache_k | cache_v].
// Fast path ws (bytes): x_bf 16.8M | wqkv 50.3M (wo reuses) | q_bf 16.8M |
// k_bf 4.2M | v_bf 4.2M | ao_bf 16.8M = 109,051,904 B. Else round-2 path.
// ---------------------------------------------------------------------------
extern "C" void kernel_launch(void* const* d_in, const int* in_sizes, int n_in,
                              void* d_out, int out_size, void* d_ws, size_t ws_size,
                              hipStream_t stream) {
  (void)in_sizes; (void)n_in; (void)out_size;
  const float* x  = (const float*)d_in[0];
  const float* fc = (const float*)d_in[1];
  const float* fs = (const float*)d_in[2];
  const float* wq = (const float*)d_in[7];
  const float* wk = (const float*)d_in[8];
  const float* wv = (const float*)d_in[9];
  const float* wo = (const float*)d_in[10];
  float* outp = (float*)d_out;
  float* ck = outp + (size_t)S_LEN * D_DIM;
  float* cv = ck + (size_t)S_LEN * NKV_ * HD_;

  if (ws_size >= 109051904ull) {
    u16* x_bf = (u16*)d_ws;                       //  8,388,608 elems
    u16* wqkv = x_bf + 8388608;                   // 25,165,824 elems
    u16* q_bf = wqkv + 25165824;                  //  8,388,608
    u16* k_bf = q_bf + 8388608;                   //  2,097,152
    u16* v_bf = k_bf + 2097152;                   //  2,097,152
    u16* ao_bf = v_bf + 2097152;                  //  8,388,608
    u16* wo_bf = wqkv;                            // reuse after qkv gemm

    // zero outp early (WO gemm accumulates into it with split-K atomics)
    hipMemsetAsync(outp, 0, (size_t)S_LEN * D_DIM * sizeof(float), stream);

    cvt_bf16<<<4096, 256, 0, stream>>>(x, x_bf, 1048576);
    cvt_bf16<<<8192, 256, 0, stream>>>(wq, wqkv, 2097152);
    cvt_bf16<<<2048, 256, 0, stream>>>(wk, wqkv + 16777216, 524288);
    cvt_bf16<<<2048, 256, 0, stream>>>(wv, wqkv + 20971520, 524288);
    gemm8<1, 3, 0><<<dim3(32, 8, 1), 512, 0, stream>>>(
        x_bf, wqkv, nullptr, q_bf, k_bf, v_bf, ck, cv, fc, fs, 6144, 64);
    cvt_bf16<<<8192, 256, 0, stream>>>(wo, wo_bf, 2097152);
    attn_bf<<<dim3(16, 32), 512, 0, stream>>>(q_bf, k_bf, v_bf, ao_bf);
    gemm8<0, 4, 1><<<dim3(16, 8, 2), 512, 0, stream>>>(
        ao_bf, wo_bf, outp, nullptr, nullptr, nullptr, nullptr, nullptr,
        fc, fs, 4096, 32);
  } else {
    float* xq = (float*)d_ws;
    float* xk = xq + (size_t)S_LEN * D_DIM;
    dim3 blk(256);
    gemm_bt<<<dim3(32, 16), blk, 0, stream>>>(x, wq, xq, 4096);
    gemm_bt<<<dim3(8, 16),  blk, 0, stream>>>(x, wk, xk, 1024);
    gemm_bt<<<dim3(8, 16),  blk, 0, stream>>>(x, wv, cv, 1024);
    rope_kernel<<<20480, 256, 0, stream>>>(xq, xk, ck, fc, fs);
    attn_mfma<<<dim3(32, 32), 512 / 2, 0, stream>>>(xq, ck, cv, xq);
    gemm_bt<<<dim3(32, 16), blk, 0, stream>>>(xq, wo, outp, 4096);
  }
}

// Round 4
// 593.239 us; speedup vs baseline: 1.1537x; 1.0638x over previous
//
#include <hip/hip_runtime.h>
#include <cstdint>

#define S_LEN 2048
#define D_DIM 4096
#define NH_ 32
#define NKV_ 8
#define HD_ 128
#define GK 4096

typedef unsigned short u16;
typedef __attribute__((ext_vector_type(4))) float f32x4;
typedef __attribute__((ext_vector_type(8))) short bf16x8;
typedef __attribute__((ext_vector_type(4))) short s16x4;

__device__ __forceinline__ short f2bf(float f) {
  union { float f; unsigned int u; } v; v.f = f;
  unsigned int r = v.u + 0x7fffu + ((v.u >> 16) & 1u);
  return (short)(r >> 16);
}

__device__ __forceinline__ void glds16(const void* g, void* l) {
  __builtin_amdgcn_global_load_lds(
      (const __attribute__((address_space(1))) void*)g,
      (__attribute__((address_space(3))) void*)l, 16, 0, 0);
}

// ---------------------------------------------------------------------------
// fp32 -> bf16 convert, 8 elems/thread
// ---------------------------------------------------------------------------
__global__ __launch_bounds__(256) void cvt_bf16(const float* __restrict__ src,
                                                u16* __restrict__ dst, int n8) {
  int i = blockIdx.x * 256 + threadIdx.x;
  if (i < n8) {
    float4 a = *(const float4*)&src[(size_t)i * 8];
    float4 b = *(const float4*)&src[(size_t)i * 8 + 4];
    bf16x8 o = { f2bf(a.x), f2bf(a.y), f2bf(a.z), f2bf(a.w),
                 f2bf(b.x), f2bf(b.y), f2bf(b.z), f2bf(b.w) };
    *(bf16x8*)&dst[(size_t)i * 8] = o;
  }
}

// ---------------------------------------------------------------------------
// 256 x (NI*64) 4-phase bf16 GEMM.  C[M x N] = A[M x 4096] * W[N x 4096]^T.
// 512 thr / 8 waves (2M x 4N), wave tile 128 x (NI*16), BK=64, double-buffered
// LDS, XOR block swizzle LDS[r][blk] = G[r][blk ^ (r&7)].
// Phases (mh,s): reads 4 af always + NI bw on ph0/ph2 (even distribution);
// ph0 stages A(kt+1), ph3 stages B(kt+2), counted s_waitcnt vmcnt(NI) once
// per K-tile keeps B(kt+2)'s NI loads in flight.
// Grid z = split-K slices (ktPer K-tiles each).
// NI=3: BN=192 (QKV grid 32x8 = 256 wg).  NI=4: BN=256 (WO 16x8x2 = 256 wg).
// MODE 0: fp32 C store (ATOMIC: unsafeAtomicAdd for split-K).
// MODE 1: fused QKV epilogue (N=6144) with RoPE.
// ---------------------------------------------------------------------------
template <int MODE, int NI, int ATOMIC>
__global__ __launch_bounds__(512, 2) void gemm8(const u16* __restrict__ Amat,
                                                const u16* __restrict__ W,
                                                float* __restrict__ C,
                                                u16* __restrict__ qbf,
                                                u16* __restrict__ kbf,
                                                u16* __restrict__ vbf,
                                                float* __restrict__ cko,
                                                float* __restrict__ cvo,
                                                const float* __restrict__ fc,
                                                const float* __restrict__ fs,
                                                int N, int ktPer) {
  __shared__ __align__(16) u16 As[2][16384];      // 2 x 32 KB
  __shared__ __align__(16) u16 Bs[2][NI * 4096];  // 2 x NI*8 KB
  const int t = threadIdx.x;
  const int lane = t & 63;
  const int wave = t >> 6;        // 0..7
  const int wr = wave >> 2;       // 0..1  M half
  const int wc = wave & 3;        // 0..3  N quarter
  const int quad = lane >> 4;
  const int L = lane & 15;
  const int bm = blockIdx.y * 256;
  const int bn = blockIdx.x * (NI * 64);
  const int dr = lane >> 3;       // row within 8-row chunk
  const int cb = lane & 7;        // 16B block within 128B row
  const int cbs = cb ^ dr;        // pre-swizzled source block
  const int kt0 = blockIdx.z * ktPer;
  const int ktN = kt0 + ktPer;

  auto stageA = [&](int tile) {   // 256 rows x 64 k = 32 KB, 4 glds/thread
    u16* dst = &As[tile & 1][0];
    const int k0 = tile << 6;
#pragma unroll
    for (int c = 0; c < 4; ++c) {
      const int chunk = wave * 4 + c;        // 0..31, 8 rows each
      const int row = chunk * 8 + dr;
      glds16(&Amat[(size_t)(bm + row) * GK + k0 + cbs * 8], &dst[chunk * 512]);
    }
  };
  auto stageB = [&](int tile) {   // NI*64 rows x 64 k, NI glds/thread
    u16* dst = &Bs[tile & 1][0];
    const int k0 = tile << 6;
#pragma unroll
    for (int c = 0; c < NI; ++c) {
      const int chunk = wave * NI + c;       // 0..8*NI-1
      const int row = chunk * 8 + dr;
      glds16(&W[(size_t)(bn + row) * GK + k0 + cbs * 8], &dst[chunk * 512]);
    }
  };

  f32x4 acc[8][NI];
#pragma unroll
  for (int i = 0; i < 8; ++i)
#pragma unroll
    for (int j = 0; j < NI; ++j) { f32x4 z = {0.f, 0.f, 0.f, 0.f}; acc[i][j] = z; }

  // prologue: tile kt0 complete, B(kt0+1) in flight (A(kt0+1) staged in ph0)
  stageB(kt0); stageA(kt0); stageB(kt0 + 1);
  if constexpr (NI == 3) asm volatile("s_waitcnt vmcnt(3)" ::: "memory");
  else                   asm volatile("s_waitcnt vmcnt(4)" ::: "memory");
  __builtin_amdgcn_s_barrier();
  __builtin_amdgcn_sched_barrier(0);

  bf16x8 af[4], bw[NI];
  const int arow = wr * 128;
  const int brow = wc * (NI * 16);

  for (int kt = kt0; kt < ktN; ++kt) {
    const u16* as = &As[kt & 1][0];
    const u16* bs = &Bs[kt & 1][0];
#pragma unroll
    for (int ph = 0; ph < 4; ++ph) {
      const int mh = ph & 1;      // ph0:(m0,s0) ph1:(m1,s0) ph2:(m0,s1) ph3:(m1,s1)
      const int s = ph >> 1;
#pragma unroll
      for (int i = 0; i < 4; ++i)
        af[i] = *(const bf16x8*)&as[(arow + mh * 64 + i * 16 + L) * 64 +
                                     (((s * 4 + quad) ^ (L & 7)) * 8)];
      if (ph == 0 || ph == 2) {
#pragma unroll
        for (int j = 0; j < NI; ++j)
          bw[j] = *(const bf16x8*)&bs[(brow + j * 16 + L) * 64 +
                                       (((s * 4 + quad) ^ (L & 7)) * 8)];
      }
      if (ph == 0 && kt + 1 < ktN) stageA(kt + 1);
      if (ph == 3 && kt + 2 < ktN) stageB(kt + 2);
      __builtin_amdgcn_s_barrier();
      asm volatile("s_waitcnt lgkmcnt(0)" ::: "memory");
      __builtin_amdgcn_sched_barrier(0);
      __builtin_amdgcn_s_setprio(1);
#pragma unroll
      for (int i = 0; i < 4; ++i)
#pragma unroll
        for (int j = 0; j < NI; ++j)
          acc[mh * 4 + i][j] = __builtin_amdgcn_mfma_f32_16x16x32_bf16(
              af[i], bw[j], acc[mh * 4 + i][j], 0, 0, 0);
      __builtin_amdgcn_s_setprio(0);
      if (ph == 3) {
        if (kt + 2 < ktN) {
          if constexpr (NI == 3) asm volatile("s_waitcnt vmcnt(3)" ::: "memory");
          else                   asm volatile("s_waitcnt vmcnt(4)" ::: "memory");
        } else {
          asm volatile("s_waitcnt vmcnt(0)" ::: "memory");
        }
      }
      __builtin_amdgcn_s_barrier();
      __builtin_amdgcn_sched_barrier(0);
    }
  }

  if (MODE == 0) {
#pragma unroll
    for (int mi = 0; mi < 8; ++mi) {
      int r0 = bm + wr * 128 + mi * 16 + quad * 4;
#pragma unroll
      for (int ni = 0; ni < NI; ++ni) {
        int c = bn + wc * (NI * 16) + ni * 16 + L;
#pragma unroll
        for (int r = 0; r < 4; ++r) {
          if (ATOMIC) unsafeAtomicAdd(&C[(size_t)(r0 + r) * N + c], acc[mi][ni][r]);
          else        C[(size_t)(r0 + r) * N + c] = acc[mi][ni][r];
        }
      }
    }
  } else {
    const float scale = 0.08838834764831845f;  // 1/sqrt(128)
#pragma unroll
    for (int mi = 0; mi < 8; ++mi) {
#pragma unroll
      for (int ni = 0; ni < NI; ++ni) {
        int c = bn + wc * (NI * 16) + ni * 16 + L;
#pragma unroll
        for (int r = 0; r < 4; ++r) {
          int srow = bm + wr * 128 + mi * 16 + 4 * quad + r;
          float v = acc[mi][ni][r];
          float partner = __shfl_xor(v, 1);  // all lanes, before branch
          if (c < 4096) {
            int p = (c >> 1) & 63;
            float co = fc[srow * 64 + p], si = fs[srow * 64 + p];
            float out = (c & 1) ? partner * si + v * co : v * co - partner * si;
            qbf[(size_t)srow * 4096 + c] = (u16)f2bf(out * scale);
          } else if (c < 5120) {
            int p = (c >> 1) & 63;
            float co = fc[srow * 64 + p], si = fs[srow * 64 + p];
            float out = (c & 1) ? partner * si + v * co : v * co - partner * si;
            int cc = c - 4096;
            cko[(size_t)srow * 1024 + cc] = out;
            kbf[(size_t)srow * 1024 + cc] = (u16)f2bf(out);
          } else {
            int cc = c - 5120;
            cvo[(size_t)srow * 1024 + cc] = v;
            vbf[(size_t)srow * 1024 + cc] = (u16)f2bf(v);
          }
        }
      }
    }
  }
}

// ---------------------------------------------------------------------------
// MFMA flash attention, bf16 in/out. 8 waves / 512 thr, QBLK=128/block.
// Round-4 changes:
//  (a) balanced 1-D grid: id & id+256 co-reside on a CU (2 blocks/CU, 512
//      blocks); qb mapping makes every pair sum to exactly 34 k-tiles
//      (was: same-qb pairs -> 64-vs-4 tile imbalance, ~2x makespan).
//  (b) T14 prefetch: tile kt+1's K/V global loads issued into regs right
//      after tile kt's LDS writes; latency hides under compute(kt).
//      NKT = 2qb+2 is always even -> clean unroll-by-2, two named reg sets.
//  (c) Ps pitch 72 -> 68 (2*68 mod 32 = 8 spreads Q4 groups over all banks).
// ---------------------------------------------------------------------------
#define PSP 68
__global__ __launch_bounds__(512, 2) void attn_bf(const u16* __restrict__ qbf,
                                                  const u16* __restrict__ kbf,
                                                  const u16* __restrict__ vbf,
                                                  u16* __restrict__ ao) {
  __shared__ __align__(16) u16 Ks[64 * 136];
  __shared__ __align__(16) u16 Vt[128 * 64];
  __shared__ __align__(16) u16 Ps[8 * 16 * PSP];
  const int t = threadIdx.x;
  const int wave = t >> 6;          // 0..7
  const int lane = t & 63;
  const int Q4 = lane >> 4;
  const int L = lane & 15;
  const int id = blockIdx.x;        // 0..511
  const int slot = id & 255;
  const int h = slot >> 3;          // 0..31
  const int k8 = slot & 7;          // 0..7
  const int qb = (id < 256) ? (2 * k8) : (15 - 2 * k8);
  const int kvh = h >> 2;
  const int qs0 = qb * 128;
  u16* Psw = &Ps[wave * 16 * PSP];

  bf16x8 qf[4];
  {
    const u16* qbase = &qbf[(size_t)(qs0 + 16 * wave + L) * D_DIM + h * HD_ + 8 * Q4];
#pragma unroll
    for (int s = 0; s < 4; ++s) qf[s] = *(const bf16x8*)&qbase[32 * s];
  }

  f32x4 o[8];
#pragma unroll
  for (int jd = 0; jd < 8; ++jd) { f32x4 z = {0.f, 0.f, 0.f, 0.f}; o[jd] = z; }
  float mold[4] = {-1e30f, -1e30f, -1e30f, -1e30f};
  float lst[4] = {0.f, 0.f, 0.f, 0.f};

  const int NKT = 2 * qb + 2;       // even

  auto loadKV = [&](int kt, bf16x8 kr[2], bf16x8 vr[2]) {
    const u16* kb = &kbf[(size_t)(kt * 64) * (NKV_ * HD_) + kvh * HD_];
    const u16* vb = &vbf[(size_t)(kt * 64) * (NKV_ * HD_) + kvh * HD_];
#pragma unroll
    for (int p = 0; p < 2; ++p) {
      int u = t + 512 * p;
      int r = u >> 4, c8 = u & 15;
      kr[p] = *(const bf16x8*)&kb[(size_t)r * (NKV_ * HD_) + c8 * 8];
    }
#pragma unroll
    for (int p = 0; p < 2; ++p) {
      int u = t + 512 * p;
      int d = u & 127, bb = u >> 7;
      const u16* vsrc = &vb[(size_t)(bb * 8) * (NKV_ * HD_) + d];
      short vv[8];
#pragma unroll
      for (int j = 0; j < 8; ++j) vv[j] = (short)vsrc[(size_t)j * (NKV_ * HD_)];
      bf16x8 pk = { vv[0], vv[1], vv[2], vv[3], vv[4], vv[5], vv[6], vv[7] };
      vr[p] = pk;
    }
  };
  auto storeKV = [&](bf16x8 kr[2], bf16x8 vr[2]) {
#pragma unroll
    for (int p = 0; p < 2; ++p) {
      int u = t + 512 * p;
      int r = u >> 4, c8 = u & 15;
      *(bf16x8*)&Ks[r * 136 + c8 * 8] = kr[p];
    }
#pragma unroll
    for (int p = 0; p < 2; ++p) {
      int u = t + 512 * p;
      int d = u & 127, bb = u >> 7;
      *(bf16x8*)&Vt[d * 64 + ((bb + d) & 7) * 8] = vr[p];
    }
  };

  auto computeTile = [&](int kt) {
    f32x4 sa[4];
#pragma unroll
    for (int jn = 0; jn < 4; ++jn) { f32x4 z = {0.f, 0.f, 0.f, 0.f}; sa[jn] = z; }
#pragma unroll
    for (int s = 0; s < 4; ++s) {
#pragma unroll
      for (int jn = 0; jn < 4; ++jn) {
        bf16x8 kf = *(const bf16x8*)&Ks[(16 * jn + L) * 136 + 32 * s + 8 * Q4];
        sa[jn] = __builtin_amdgcn_mfma_f32_16x16x32_bf16(qf[s], kf, sa[jn], 0, 0, 0);
      }
    }

    const int gq0 = qs0 + 16 * wave + 4 * Q4;
    const int gk0 = kt * 64 + L;
    float rmax[4];
#pragma unroll
    for (int r = 0; r < 4; ++r) {
#pragma unroll
      for (int jn = 0; jn < 4; ++jn)
        if (gk0 + 16 * jn > gq0 + r) sa[jn][r] = -1e30f;
      rmax[r] = fmaxf(fmaxf(sa[0][r], sa[1][r]), fmaxf(sa[2][r], sa[3][r]));
    }
#pragma unroll
    for (int m = 1; m < 16; m <<= 1) {
#pragma unroll
      for (int r = 0; r < 4; ++r) rmax[r] = fmaxf(rmax[r], __shfl_xor(rmax[r], m));
    }
    float p_[4][4], rsum[4], alpha[4];
#pragma unroll
    for (int r = 0; r < 4; ++r) {
      float mnew = fmaxf(mold[r], rmax[r]);
      alpha[r] = __expf(mold[r] - mnew);
#pragma unroll
      for (int jn = 0; jn < 4; ++jn) p_[jn][r] = __expf(sa[jn][r] - mnew);
      rsum[r] = (p_[0][r] + p_[1][r]) + (p_[2][r] + p_[3][r]);
      mold[r] = mnew;
    }
#pragma unroll
    for (int m = 1; m < 16; m <<= 1) {
#pragma unroll
      for (int r = 0; r < 4; ++r) rsum[r] += __shfl_xor(rsum[r], m);
    }
#pragma unroll
    for (int r = 0; r < 4; ++r) lst[r] = lst[r] * alpha[r] + rsum[r];
#pragma unroll
    for (int jd = 0; jd < 8; ++jd)
#pragma unroll
      for (int r = 0; r < 4; ++r) o[jd][r] *= alpha[r];

#pragma unroll
    for (int r = 0; r < 4; ++r)
#pragma unroll
      for (int jn = 0; jn < 4; ++jn)
        Psw[(4 * Q4 + r) * PSP + 16 * jn + L] = (u16)f2bf(p_[jn][r]);
    asm volatile("s_waitcnt lgkmcnt(0)" ::: "memory");

#pragma unroll
    for (int s2 = 0; s2 < 2; ++s2) {
      bf16x8 pa = *(const bf16x8*)&Psw[L * PSP + 32 * s2 + 8 * Q4];
#pragma unroll
      for (int jd = 0; jd < 8; ++jd) {
        bf16x8 vf = *(const bf16x8*)&Vt[(16 * jd + L) * 64 + ((4 * s2 + Q4 + L) & 7) * 8];
        o[jd] = __builtin_amdgcn_mfma_f32_16x16x32_bf16(pa, vf, o[jd], 0, 0, 0);
      }
    }
  };

  bf16x8 krA[2], vrA[2], krB[2], vrB[2];
  loadKV(0, krA, vrA);
  for (int kt = 0; kt < NKT; kt += 2) {
    __syncthreads();                 // prev compute done reading Ks/Vt
    storeKV(krA, vrA);               // waits on krA/vrA loads
    loadKV(kt + 1, krB, vrB);        // kt+1 <= NKT-1 (NKT even)
    __syncthreads();
    computeTile(kt);                 // hides krB/vrB load latency
    __syncthreads();
    storeKV(krB, vrB);
    if (kt + 2 < NKT) loadKV(kt + 2, krA, vrA);
    __syncthreads();
    computeTile(kt + 1);
  }

  float inv[4];
#pragma unroll
  for (int r = 0; r < 4; ++r) inv[r] = 1.0f / lst[r];
#pragma unroll
  for (int r = 0; r < 4; ++r) {
    u16* dst = &ao[(size_t)(qs0 + 16 * wave + 4 * Q4 + r) * D_DIM + h * HD_ + L];
#pragma unroll
    for (int jd = 0; jd < 8; ++jd) dst[16 * jd] = (u16)f2bf(o[jd][r] * inv[r]);
  }
}

// ===========================================================================
// Fallback path (round-2 kernels, verified) for small ws_size
// ===========================================================================
#define LDA 40
__global__ __launch_bounds__(256) void gemm_bt(const float* __restrict__ A,
                                               const float* __restrict__ W,
                                               float* __restrict__ C, int N) {
  __shared__ short As[128 * LDA];
  __shared__ short Bs[128 * LDA];
  const int t = threadIdx.x;
  const int lane = t & 63;
  const int wave = t >> 6;
  const int wm = (wave >> 1) * 64;
  const int wn = (wave & 1) * 64;
  const int quad = lane >> 4;
  const int l15 = lane & 15;
  const int bm = blockIdx.y * 128;
  const int bn = blockIdx.x * 128;
  f32x4 acc[4][4];
#pragma unroll
  for (int i = 0; i < 4; ++i)
#pragma unroll
    for (int j = 0; j < 4; ++j) { f32x4 z = {0.f, 0.f, 0.f, 0.f}; acc[i][j] = z; }
  for (int k0 = 0; k0 < GK; k0 += 32) {
    __syncthreads();
#pragma unroll
    for (int p = 0; p < 4; ++p) {
      int idx = p * 256 + t;
      int row = idx >> 3;
      int c4 = (idx & 7) * 4;
      const float4 av = *(const float4*)&A[(size_t)(bm + row) * GK + k0 + c4];
      const float4 wv = *(const float4*)&W[(size_t)(bn + row) * GK + k0 + c4];
      s16x4 a4 = { f2bf(av.x), f2bf(av.y), f2bf(av.z), f2bf(av.w) };
      s16x4 w4 = { f2bf(wv.x), f2bf(wv.y), f2bf(wv.z), f2bf(wv.w) };
      *(s16x4*)&As[row * LDA + c4] = a4;
      *(s16x4*)&Bs[row * LDA + c4] = w4;
    }
    __syncthreads();
    bf16x8 af[4], bfr[4];
#pragma unroll
    for (int i = 0; i < 4; ++i) {
      af[i]  = *(const bf16x8*)&As[(wm + i * 16 + l15) * LDA + quad * 8];
      bfr[i] = *(const bf16x8*)&Bs[(wn + i * 16 + l15) * LDA + quad * 8];
    }
#pragma unroll
    for (int i = 0; i < 4; ++i)
#pragma unroll
      for (int j = 0; j < 4; ++j)
        acc[i][j] = __builtin_amdgcn_mfma_f32_16x16x32_bf16(af[i], bfr[j], acc[i][j], 0, 0, 0);
  }
#pragma unroll
  for (int i = 0; i < 4; ++i) {
    int r0 = bm + wm + i * 16 + quad * 4;
#pragma unroll
    for (int j = 0; j < 4; ++j) {
      int c = bn + wn + j * 16 + l15;
#pragma unroll
      for (int r = 0; r < 4; ++r) C[(size_t)(r0 + r) * N + c] = acc[i][j][r];
    }
  }
}

__global__ __launch_bounds__(256) void rope_kernel(float* __restrict__ xq,
                                                   const float* __restrict__ xk,
                                                   float* __restrict__ cko,
                                                   const float* __restrict__ fc,
                                                   const float* __restrict__ fs) {
  int i = blockIdx.x * 256 + threadIdx.x;
  const int NQP = S_LEN * NH_ * (HD_ / 2);
  if (i < NQP) {
    int s = i >> 11; int rem = i & 2047; int p = rem & 63;
    float c = fc[s * 64 + p], sn = fs[s * 64 + p];
    float2 v = *(const float2*)&xq[(size_t)s * D_DIM + 2 * rem];
    *(float2*)&xq[(size_t)s * D_DIM + 2 * rem] =
        make_float2(v.x * c - v.y * sn, v.x * sn + v.y * c);
  } else {
    int j = i - NQP; int s = j >> 9; int rem = j & 511; int p = rem & 63;
    float c = fc[s * 64 + p], sn = fs[s * 64 + p];
    float2 v = *(const float2*)&xk[(size_t)s * (NKV_ * HD_) + 2 * rem];
    *(float2*)&cko[(size_t)s * (NKV_ * HD_) + 2 * rem] =
        make_float2(v.x * c - v.y * sn, v.x * sn + v.y * c);
  }
}

__global__ __launch_bounds__(256, 3) void attn_mfma(const float* __restrict__ xq,
                                                    const float* __restrict__ ck,
                                                    const float* __restrict__ cv,
                                                    float* __restrict__ outp) {
  __shared__ __align__(16) short Ks[64 * 136];
  __shared__ __align__(16) short Vt[128 * 64];
  __shared__ __align__(16) short Ps[4 * 16 * 72];
  const int t = threadIdx.x;
  const int wave = t >> 6;
  const int lane = t & 63;
  const int Q4 = lane >> 4;
  const int L = lane & 15;
  const int h = blockIdx.y;
  const int qb = 31 - (int)blockIdx.x;
  const int kvh = h >> 2;
  const int qs0 = qb * 64;
  const float scale = 0.08838834764831845f;
  short* Psw = &Ps[wave * 16 * 72];
  bf16x8 qf[4];
  {
    const float* qbase = &xq[(size_t)(qs0 + 16 * wave + L) * D_DIM + h * HD_ + 8 * Q4];
#pragma unroll
    for (int s = 0; s < 4; ++s) {
      float4 a = *(const float4*)&qbase[32 * s];
      float4 b = *(const float4*)&qbase[32 * s + 4];
      bf16x8 q8 = { f2bf(a.x * scale), f2bf(a.y * scale), f2bf(a.z * scale), f2bf(a.w * scale),
                    f2bf(b.x * scale), f2bf(b.y * scale), f2bf(b.z * scale), f2bf(b.w * scale) };
      qf[s] = q8;
    }
  }
  f32x4 o[8];
#pragma unroll
  for (int jd = 0; jd < 8; ++jd) { f32x4 z = {0.f, 0.f, 0.f, 0.f}; o[jd] = z; }
  float mold[4] = {-1e30f, -1e30f, -1e30f, -1e30f};
  float lst[4] = {0.f, 0.f, 0.f, 0.f};
  for (int kt = 0; kt <= qb; ++kt) {
    __syncthreads();
    const float* ckb = &ck[(size_t)(kt * 64) * (NKV_ * HD_) + kvh * HD_];
    const float* cvb = &cv[(size_t)(kt * 64) * (NKV_ * HD_) + kvh * HD_];
#pragma unroll
    for (int p = 0; p < 8; ++p) {
      int i = t + 256 * p;
      int r = i >> 5, c4 = (i & 31) * 4;
      float4 v = *(const float4*)&ckb[(size_t)r * (NKV_ * HD_) + c4];
      s16x4 k4 = { f2bf(v.x), f2bf(v.y), f2bf(v.z), f2bf(v.w) };
      *(s16x4*)&Ks[r * 136 + c4] = k4;
    }
#pragma unroll
    for (int p = 0; p < 4; ++p) {
      int u = t + 256 * p;
      int d = u & 127, bb = u >> 7;
      float vv[8];
#pragma unroll
      for (int j = 0; j < 8; ++j) vv[j] = cvb[(size_t)(bb * 8 + j) * (NKV_ * HD_) + d];
      bf16x8 pk = { f2bf(vv[0]), f2bf(vv[1]), f2bf(vv[2]), f2bf(vv[3]),
                    f2bf(vv[4]), f2bf(vv[5]), f2bf(vv[6]), f2bf(vv[7]) };
      *(bf16x8*)&Vt[d * 64 + ((bb + d) & 7) * 8] = pk;
    }
    __syncthreads();
    f32x4 sa[4];
#pragma unroll
    for (int jn = 0; jn < 4; ++jn) { f32x4 z = {0.f, 0.f, 0.f, 0.f}; sa[jn] = z; }
#pragma unroll
    for (int s = 0; s < 4; ++s) {
#pragma unroll
      for (int jn = 0; jn < 4; ++jn) {
        bf16x8 kf = *(const bf16x8*)&Ks[(16 * jn + L) * 136 + 32 * s + 8 * Q4];
        sa[jn] = __builtin_amdgcn_mfma_f32_16x16x32_bf16(qf[s], kf, sa[jn], 0, 0, 0);
      }
    }
    const int gq0 = qs0 + 16 * wave + 4 * Q4;
    const int gk0 = kt * 64 + L;
    float rmax[4];
#pragma unroll
    for (int r = 0; r < 4; ++r) {
#pragma unroll
      for (int jn = 0; jn < 4; ++jn)
        if (gk0 + 16 * jn > gq0 + r) sa[jn][r] = -1e30f;
      rmax[r] = fmaxf(fmaxf(sa[0][r], sa[1][r]), fmaxf(sa[2][r], sa[3][r]));
    }
#pragma unroll
    for (int m = 1; m < 16; m <<= 1) {
#pragma unroll
      for (int r = 0; r < 4; ++r) rmax[r] = fmaxf(rmax[r], __shfl_xor(rmax[r], m));
    }
    float p_[4][4], rsum[4], alpha[4];
#pragma unroll
    for (int r = 0; r < 4; ++r) {
      float mnew = fmaxf(mold[r], rmax[r]);
      alpha[r] = __expf(mold[r] - mnew);
#pragma unroll
      for (int jn = 0; jn < 4; ++jn) p_[jn][r] = __expf(sa[jn][r] - mnew);
      rsum[r] = (p_[0][r] + p_[1][r]) + (p_[2][r] + p_[3][r]);
      mold[r] = mnew;
    }
#pragma unroll
    for (int m = 1; m < 16; m <<= 1) {
#pragma unroll
      for (int r = 0; r < 4; ++r) rsum[r] += __shfl_xor(rsum[r], m);
    }
#pragma unroll
    for (int r = 0; r < 4; ++r) lst[r] = lst[r] * alpha[r] + rsum[r];
#pragma unroll
    for (int jd = 0; jd < 8; ++jd)
#pragma unroll
      for (int r = 0; r < 4; ++r) o[jd][r] *= alpha[r];
#pragma unroll
    for (int r = 0; r < 4; ++r)
#pragma unroll
      for (int jn = 0; jn < 4; ++jn)
        Psw[(4 * Q4 + r) * 72 + 16 * jn + L] = f2bf(p_[jn][r]);
    asm volatile("s_waitcnt lgkmcnt(0)" ::: "memory");
#pragma unroll
    for (int s2 = 0; s2 < 2; ++s2) {
      bf16x8 pa = *(const bf16x8*)&Psw[L * 72 + 32 * s2 + 8 * Q4];
#pragma unroll
      for (int jd = 0; jd < 8; ++jd) {
        bf16x8 vf = *(const bf16x8*)&Vt[(16 * jd + L) * 64 + ((4 * s2 + Q4 + L) & 7) * 8];
        o[jd] = __builtin_amdgcn_mfma_f32_16x16x32_bf16(pa, vf, o[jd], 0, 0, 0);
      }
    }
  }
  float inv[4];
#pragma unroll
  for (int r = 0; r < 4; ++r) inv[r] = 1.0f / lst[r];
#pragma unroll
  for (int r = 0; r < 4; ++r) {
    float* dst = &outp[(size_t)(qs0 + 16 * wave + 4 * Q4 + r) * D_DIM + h * HD_ + L];
#pragma unroll
    for (int jd = 0; jd < 8; ++jd) dst[16 * jd] = o[jd][r] * inv[r];
  }
}

// ---------------------------------------------------------------------------
// Inputs: 0:x 1:fc 2:fs 3:mask(unused) 4:idx(unused) 5:ck0 6:cv0 7:wq 8:wk
// 9:wv 10:wo. d_out = [out | cache_k | cache_v].
// Fast path ws (bytes): x_bf 16.8M | wqkv 50.3M (wo reuses) | q_bf 16.8M |
// k_bf 4.2M | v_bf 4.2M | ao_bf 16.8M = 109,051,904 B. Else round-2 path.
// ---------------------------------------------------------------------------
extern "C" void kernel_launch(void* const* d_in, const int* in_sizes, int n_in,
                              void* d_out, int out_size, void* d_ws, size_t ws_size,
                              hipStream_t stream) {
  (void)in_sizes; (void)n_in; (void)out_size;
  const float* x  = (const float*)d_in[0];
  const float* fc = (const float*)d_in[1];
  const float* fs = (const float*)d_in[2];
  const float* wq = (const float*)d_in[7];
  const float* wk = (const float*)d_in[8];
  const float* wv = (const float*)d_in[9];
  const float* wo = (const float*)d_in[10];
  float* outp = (float*)d_out;
  float* ck = outp + (size_t)S_LEN * D_DIM;
  float* cv = ck + (size_t)S_LEN * NKV_ * HD_;

  if (ws_size >= 109051904ull) {
    u16* x_bf = (u16*)d_ws;                       //  8,388,608 elems
    u16* wqkv = x_bf + 8388608;                   // 25,165,824 elems
    u16* q_bf = wqkv + 25165824;                  //  8,388,608
    u16* k_bf = q_bf + 8388608;                   //  2,097,152
    u16* v_bf = k_bf + 2097152;                   //  2,097,152
    u16* ao_bf = v_bf + 2097152;                  //  8,388,608
    u16* wo_bf = wqkv;                            // reuse after qkv gemm

    // zero outp early (WO gemm accumulates into it with split-K atomics)
    hipMemsetAsync(outp, 0, (size_t)S_LEN * D_DIM * sizeof(float), stream);

    cvt_bf16<<<4096, 256, 0, stream>>>(x, x_bf, 1048576);
    cvt_bf16<<<8192, 256, 0, stream>>>(wq, wqkv, 2097152);
    cvt_bf16<<<2048, 256, 0, stream>>>(wk, wqkv + 16777216, 524288);
    cvt_bf16<<<2048, 256, 0, stream>>>(wv, wqkv + 20971520, 524288);
    gemm8<1, 3, 0><<<dim3(32, 8, 1), 512, 0, stream>>>(
        x_bf, wqkv, nullptr, q_bf, k_bf, v_bf, ck, cv, fc, fs, 6144, 64);
    cvt_bf16<<<8192, 256, 0, stream>>>(wo, wo_bf, 2097152);
    attn_bf<<<dim3(512), 512, 0, stream>>>(q_bf, k_bf, v_bf, ao_bf);
    gemm8<0, 4, 1><<<dim3(16, 8, 2), 512, 0, stream>>>(
        ao_bf, wo_bf, outp, nullptr, nullptr, nullptr, nullptr, nullptr,
        fc, fs, 4096, 32);
  } else {
    float* xq = (float*)d_ws;
    float* xk = xq + (size_t)S_LEN * D_DIM;
    dim3 blk(256);
    gemm_bt<<<dim3(32, 16), blk, 0, stream>>>(x, wq, xq, 4096);
    gemm_bt<<<dim3(8, 16),  blk, 0, stream>>>(x, wk, xk, 1024);
    gemm_bt<<<dim3(8, 16),  blk, 0, stream>>>(x, wv, cv, 1024);
    rope_kernel<<<20480, 256, 0, stream>>>(xq, xk, ck, fc, fs);
    attn_mfma<<<dim3(32, 32), 512 / 2, 0, stream>>>(xq, ck, cv, xq);
    gemm_bt<<<dim3(32, 16), blk, 0, stream>>>(xq, wo, outp, 4096);
  }
}